// Round 3
// baseline (155.796 us; speedup 1.0000x reference)
//
#include <hip/hip_runtime.h>

// ---------------------------------------------------------------------------
// Per-batch dynamic conv stack + polynomial attention (f32).
//   feature (8,360) = mean(thumb,(2,3)) @ Wm + bm
//   conv_stack: residual + [3x conv3x3(SAME,leaky 0.2)] -> [5x conv1x1(leaky)]
//   attention:  out = y * (1 + prod_i(a*h + b*w + c*y + d)) per channel
// Outputs: x_out (8,3,512,512) then thumb_out (8,3,64,64), flat f32.
//
// R10: phase-aligned LDS mapping. Model: ds_*_b128 runs in 16-lane phases;
// a phase is conflict-free iff its 16 lanes cover 256B contiguous. R9's
// 18-quad strips straddled phases (3 of 4 phases mixed rows -> ~1.5x) =
// the residual 6.0M conflict cycles (22% of time).
//   * Tile 16 rows x 120 cols: halo = 132 dwords = 33 quads -> conv strips
//     are 32 quad-groups = exactly 32 lanes; EVERY 16-lane phase of every
//     conv read/write is 16 contiguous quads. Conflict-free by construction,
//     independent of STRD or phase alignment details.
//   * conv1 320 units (2 passes, dual acc), conv2 288, conv3 512 = 2 exact
//     passes; each thread produces 2 output quads.
//   * Residual re-read from GLOBAL at epilogue (L2-hot) instead of held in
//     registers: -24 VGPR, -24 LDS reads/block, simpler liveness.
//   * 512 = 4x120 + 32: each row-band has 4 full + 1 remainder tile
//     (stores guarded); ~15% compute waste, bought conflict-freedom.
//   * 1312 blocks, LDS 34.9KB -> 4 blocks/CU, (256,4) -> VGPR<=128.
// ---------------------------------------------------------------------------

#define LEAKY(v) fmaxf((v), 0.2f * (v))

constexpr int STRD = 132;           // dwords per buffered row (image cols -4..127)
constexpr int ROWS0 = 22;           // rows -3..18
constexpr int CHS  = ROWS0 * STRD;  // 2904 dwords per channel slab
constexpr int BUFSZ = 3 * CHS + 4;  // 34.9KB

__global__ __launch_bounds__(384) void prep_kernel(
    const float* __restrict__ thumb, const float* __restrict__ Wm,
    const float* __restrict__ bm, float* __restrict__ feat)
{
    const int b = blockIdx.x;                // 8 blocks
    const int t = threadIdx.x;               // 384
    const int ch = t >> 7;                   // 0..2
    const int l  = t & 127;
    const float4* p = (const float4*)(thumb + (size_t)b * 3 * 4096);
    float s = 0.f;
#pragma unroll
    for (int k = 0; k < 8; ++k) {
        float4 v = p[ch * 1024 + l + k * 128];
        s += v.x + v.y + v.z + v.w;
    }
    __shared__ float red[384];
    red[t] = s;
    __syncthreads();
    for (int off = 64; off > 0; off >>= 1) {
        if (l < off) red[t] += red[t + off];
        __syncthreads();
    }
    if (t < 360) {
        const float sc = 1.f / 4096.f;
        const float m0 = red[0] * sc, m1 = red[128] * sc, m2 = red[256] * sc;
        feat[b * 360 + t] =
            fmaf(m0, Wm[t], fmaf(m1, Wm[360 + t], fmaf(m2, Wm[720 + t], bm[t])));
    }
}

// 3x3 conv over a strip of R output rows x 4 cols, all 3 och.
// gx: buffer dword index of the output quad (multiple of 4, 0..124).
// Buffer col d = image col d-4. Reads A at gx-4 (clamped at gx==0: feeds
// only the discarded image col -4), B at gx, C at gx+4.
template<int R>
__device__ __forceinline__ void conv_rows(
    const float* __restrict__ buf, const float* __restrict__ fw,
    int r0, int gx, float4 acc[][3])
{
    const float b0 = fw[81], b1 = fw[82], b2 = fw[83];
#pragma unroll
    for (int j = 0; j < R; ++j) {
        acc[j][0] = make_float4(b0, b0, b0, b0);
        acc[j][1] = make_float4(b1, b1, b1, b1);
        acc[j][2] = make_float4(b2, b2, b2, b2);
    }
    const int gA = (gx == 0) ? 0 : gx - 4;
#pragma unroll
    for (int ich = 0; ich < 3; ++ich) {
#pragma unroll
        for (int ri = 0; ri < R + 2; ++ri) {
            const int idx = ich * CHS + (r0 + 2 + ri) * STRD;
            const float4 A = *(const float4*)&buf[idx + gA];     // cols gx-8..gx-5 (img)
            const float4 B = *(const float4*)&buf[idx + gx];     // output quad cols
            const float4 C = *(const float4*)&buf[idx + gx + 4];
#pragma unroll
            for (int j = 0; j < R; ++j) {
                const int dy = ri - j;
                if (dy < 0 || dy > 2) continue;
#pragma unroll
                for (int oc = 0; oc < 3; ++oc) {
                    const float w0 = fw[oc * 27 + ich * 9 + dy * 3 + 0];
                    const float w1 = fw[oc * 27 + ich * 9 + dy * 3 + 1];
                    const float w2 = fw[oc * 27 + ich * 9 + dy * 3 + 2];
                    float4& a = acc[j][oc];
                    a.x = fmaf(A.w, w0, fmaf(B.x, w1, fmaf(B.y, w2, a.x)));
                    a.y = fmaf(B.x, w0, fmaf(B.y, w1, fmaf(B.z, w2, a.y)));
                    a.z = fmaf(B.y, w0, fmaf(B.z, w1, fmaf(B.w, w2, a.z)));
                    a.w = fmaf(B.z, w0, fmaf(B.w, w1, fmaf(C.x, w2, a.w)));
                }
            }
        }
    }
}

__device__ __forceinline__ void write_strip(
    float* __restrict__ buf, int r0, int gx, float4 acc[][3])
{
#pragma unroll
    for (int j = 0; j < 2; ++j)
#pragma unroll
        for (int oc = 0; oc < 3; ++oc) {
            float4 v = acc[j][oc];
            v.x = LEAKY(v.x); v.y = LEAKY(v.y); v.z = LEAKY(v.z); v.w = LEAKY(v.w);
            *(float4*)&buf[oc * CHS + (r0 + j + 3) * STRD + gx] = v;
        }
}

__global__ __launch_bounds__(256, 4) void conv_att_kernel(
    const float* __restrict__ x, const float* __restrict__ thumb,
    const float* __restrict__ feat, float* __restrict__ out)
{
    __shared__ float buf[BUFSZ];

    int id = blockIdx.x;
    const float* src; float* dst; int H, W, b, trow, tcol;
    if (id < 1280) {                 // big: 8 b x 32 row-bands x 5 col tiles
        b = id / 160; const int t = id - b * 160;
        const int band = t / 5, ct = t - band * 5;
        H = 512; W = 512; trow = band * 16; tcol = ct * 120;
        src = x; dst = out;
    } else {                         // thumb: 8 batches x 4 row-bands
        const int i2 = id - 1280;
        b = i2 >> 2; trow = (i2 & 3) * 16; tcol = 0;
        H = 64; W = 64; src = thumb;
        dst = out + (size_t)8 * 3 * 512 * 512;
    }
    const float* fb = feat + b * 360;    // uniform -> scalar loads
    const int tid = threadIdx.x;

    // ---- stage0 load: 2178 float4 slots (3ch x 22 rows x 33 quads) ----
    const float* sbg = src + (size_t)b * 3 * H * W;
    for (int q = tid; q < 2178; q += 256) {
        const int c = q / 726;                 // 726 = 22*33
        const int rem = q - c * 726;
        const int mr = rem / 33;
        const int mq = rem - mr * 33;
        const int gr = trow + mr - 3;
        const int gc0 = tcol + 4 * mq - 4;
        const bool rok = (unsigned)gr < (unsigned)H;
        const float* gp = sbg + (size_t)c * H * W + (size_t)(rok ? gr : 0) * W;
        float4 v;
        if (rok && (unsigned)gc0 <= (unsigned)(W - 4)) {
            v = *(const float4*)&gp[gc0];      // interior fast path
        } else {
            v.x = (rok && (unsigned)(gc0 + 0) < (unsigned)W) ? gp[gc0 + 0] : 0.f;
            v.y = (rok && (unsigned)(gc0 + 1) < (unsigned)W) ? gp[gc0 + 1] : 0.f;
            v.z = (rok && (unsigned)(gc0 + 2) < (unsigned)W) ? gp[gc0 + 2] : 0.f;
            v.w = (rok && (unsigned)(gc0 + 3) < (unsigned)W) ? gp[gc0 + 3] : 0.f;
        }
        *(float4*)&buf[c * CHS + mr * STRD + 4 * mq] = v;
    }
    __syncthreads();

    // ---- conv1: 10 strips (rows -2..17, R=2) x 32 quads = 320 units ----
    // pass1 = units 0..255 (strips 0..7), pass2 = 256..319 (strips 8,9).
    // Both passes computed before any write (in-place overwrite hazard).
    float4 acc1[2][3], acc2[2][3];
    {
        const int s = tid >> 5, g = tid & 31;
        conv_rows<2>(buf, fb, 2 * s - 2, 4 * g, acc1);
    }
    const bool p2a = tid < 64;
    if (p2a) {
        const int u = tid + 256;
        const int s = u >> 5, g = u & 31;
        conv_rows<2>(buf, fb, 2 * s - 2, 4 * g, acc2);
    }
    __syncthreads();
    {
        const int s = tid >> 5, g = tid & 31;
        write_strip(buf, 2 * s - 2, 4 * g, acc1);
        if (p2a) {
            const int u = tid + 256;
            const int s2 = u >> 5, g2 = u & 31;
            write_strip(buf, 2 * s2 - 2, 4 * g2, acc2);
        }
    }
    __syncthreads();

    // ---- conv2: 9 strips (rows -1..16, R=2) x 32 quads = 288 units ----
    {
        const int s = tid >> 5, g = tid & 31;
        conv_rows<2>(buf, fb + 84, 2 * s - 1, 4 * g, acc1);
    }
    const bool p2b = tid < 32;
    if (p2b) {
        const int u = tid + 256;
        const int s = u >> 5, g = u & 31;
        conv_rows<2>(buf, fb + 84, 2 * s - 1, 4 * g, acc2);
    }
    __syncthreads();
    {
        const int s = tid >> 5, g = tid & 31;
        write_strip(buf, 2 * s - 1, 4 * g, acc1);
        if (p2b) {
            const int u = tid + 256;
            const int s2 = u >> 5, g2 = u & 31;
            write_strip(buf, 2 * s2 - 1, 4 * g2, acc2);
        }
    }
    __syncthreads();

    // ---- conv3 (rows 0..15 x 32 quads = 512 units = 2 exact passes)
    //      + 1x1 chain + residual(global) + attention + store ----
    const float invH = 1.f / (float)H;
    const float invW = 1.f / (float)W;
#pragma unroll
    for (int pass = 0; pass < 2; ++pass) {
        const int u = tid + pass * 256;
        const int s3 = u >> 5;           // output row 0..15
        const int gq = u & 31;           // buffer quad 0..31
        float4 y[1][3];
        conv_rows<1>(buf, fb + 168, s3, 4 * gq, y);
        float4 y0 = y[0][0], y1 = y[0][1], y2 = y[0][2];
        y0.x = LEAKY(y0.x); y0.y = LEAKY(y0.y); y0.z = LEAKY(y0.z); y0.w = LEAKY(y0.w);
        y1.x = LEAKY(y1.x); y1.y = LEAKY(y1.y); y1.z = LEAKY(y1.z); y1.w = LEAKY(y1.w);
        y2.x = LEAKY(y2.x); y2.y = LEAKY(y2.y); y2.z = LEAKY(y2.z); y2.w = LEAKY(y2.w);

        // 5x conv1x1 chain in registers
#pragma unroll
        for (int lay = 0; lay < 5; ++lay) {
            const float* fw = fb + 252 + lay * 12;
            const float w00 = fw[0], w01 = fw[1], w02 = fw[2];
            const float w10 = fw[3], w11 = fw[4], w12 = fw[5];
            const float w20 = fw[6], w21 = fw[7], w22 = fw[8];
            const float c0 = fw[9], c1 = fw[10], c2 = fw[11];
            float4 z0, z1, z2;
            z0.x = fmaf(y0.x, w00, fmaf(y1.x, w01, fmaf(y2.x, w02, c0)));
            z0.y = fmaf(y0.y, w00, fmaf(y1.y, w01, fmaf(y2.y, w02, c0)));
            z0.z = fmaf(y0.z, w00, fmaf(y1.z, w01, fmaf(y2.z, w02, c0)));
            z0.w = fmaf(y0.w, w00, fmaf(y1.w, w01, fmaf(y2.w, w02, c0)));
            z1.x = fmaf(y0.x, w10, fmaf(y1.x, w11, fmaf(y2.x, w12, c1)));
            z1.y = fmaf(y0.y, w10, fmaf(y1.y, w11, fmaf(y2.y, w12, c1)));
            z1.z = fmaf(y0.z, w10, fmaf(y1.z, w11, fmaf(y2.z, w12, c1)));
            z1.w = fmaf(y0.w, w10, fmaf(y1.w, w11, fmaf(y2.w, w12, c1)));
            z2.x = fmaf(y0.x, w20, fmaf(y1.x, w21, fmaf(y2.x, w22, c2)));
            z2.y = fmaf(y0.y, w20, fmaf(y1.y, w21, fmaf(y2.y, w22, c2)));
            z2.z = fmaf(y0.z, w20, fmaf(y1.z, w21, fmaf(y2.z, w22, c2)));
            z2.w = fmaf(y0.w, w20, fmaf(y1.w, w21, fmaf(y2.w, w22, c2)));
            y0.x = LEAKY(z0.x); y0.y = LEAKY(z0.y); y0.z = LEAKY(z0.z); y0.w = LEAKY(z0.w);
            y1.x = LEAKY(z1.x); y1.y = LEAKY(z1.y); y1.z = LEAKY(z1.z); y1.w = LEAKY(z1.w);
            y2.x = LEAKY(z2.x); y2.y = LEAKY(z2.y); y2.z = LEAKY(z2.z); y2.w = LEAKY(z2.w);
        }

        const int gr = trow + s3;
        const int c0i = tcol + 4 * gq - 4;   // image col of quad start
        if (gq >= 1 && c0i <= W - 4) {       // valid, in-image, non-duplicate
            const float h = (float)gr * invH;
            const float wbase = (float)c0i * invW;
            const float4 wv = make_float4(wbase, wbase + invW,
                                          wbase + 2.f * invW, wbase + 3.f * invW);
#pragma unroll
            for (int ch = 0; ch < 3; ++ch) {
                // residual from global (tile is L2-hot from stage0)
                const float4 res =
                    *(const float4*)&sbg[(size_t)ch * H * W + (size_t)gr * W + c0i];
                const float* fp = fb + 312 + ch * 16;
                const float pa0 = fp[0], pb0 = fp[1], pc0 = fp[2], pd0 = fp[3];
                const float pa1 = fp[4], pb1 = fp[5], pc1 = fp[6], pd1 = fp[7];
                const float pa2 = fp[8], pb2 = fp[9], pc2 = fp[10], pd2 = fp[11];
                const float pa3 = fp[12], pb3 = fp[13], pc3 = fp[14], pd3 = fp[15];
                const float4 yv = (ch == 0) ? y0 : (ch == 1) ? y1 : y2;
                float4 v;
                v.x = yv.x + res.x;
                v.y = yv.y + res.y;
                v.z = yv.z + res.z;
                v.w = yv.w + res.w;
                const float t0 = fmaf(pa0, h, pd0), t1 = fmaf(pa1, h, pd1);
                const float t2 = fmaf(pa2, h, pd2), t3 = fmaf(pa3, h, pd3);
                float4 o;
                float a0 = fmaf(pb0, wv.x, fmaf(pc0, v.x, t0));
                a0 *= fmaf(pb1, wv.x, fmaf(pc1, v.x, t1));
                a0 *= fmaf(pb2, wv.x, fmaf(pc2, v.x, t2));
                a0 *= fmaf(pb3, wv.x, fmaf(pc3, v.x, t3));
                o.x = v.x * (1.f + a0);
                float a1 = fmaf(pb0, wv.y, fmaf(pc0, v.y, t0));
                a1 *= fmaf(pb1, wv.y, fmaf(pc1, v.y, t1));
                a1 *= fmaf(pb2, wv.y, fmaf(pc2, v.y, t2));
                a1 *= fmaf(pb3, wv.y, fmaf(pc3, v.y, t3));
                o.y = v.y * (1.f + a1);
                float a2 = fmaf(pb0, wv.z, fmaf(pc0, v.z, t0));
                a2 *= fmaf(pb1, wv.z, fmaf(pc1, v.z, t1));
                a2 *= fmaf(pb2, wv.z, fmaf(pc2, v.z, t2));
                a2 *= fmaf(pb3, wv.z, fmaf(pc3, v.z, t3));
                o.z = v.z * (1.f + a2);
                float a3 = fmaf(pb0, wv.w, fmaf(pc0, v.w, t0));
                a3 *= fmaf(pb1, wv.w, fmaf(pc1, v.w, t1));
                a3 *= fmaf(pb2, wv.w, fmaf(pc2, v.w, t2));
                a3 *= fmaf(pb3, wv.w, fmaf(pc3, v.w, t3));
                o.w = v.w * (1.f + a3);
                *(float4*)&dst[((size_t)(b * 3 + ch) * H + gr) * W + c0i] = o;
            }
        }
    }
}

extern "C" void kernel_launch(void* const* d_in, const int* in_sizes, int n_in,
                              void* d_out, int out_size, void* d_ws, size_t ws_size,
                              hipStream_t stream) {
    const float* x = (const float*)d_in[0];       // (8,3,512,512)
    const float* thumb = (const float*)d_in[1];   // (8,3,64,64)
    const float* Wm = (const float*)d_in[2];      // (3,360)
    const float* bm = (const float*)d_in[3];      // (360,)
    float* out = (float*)d_out;
    float* feat = (float*)d_ws;                   // (8,360)

    prep_kernel<<<8, 384, 0, stream>>>(thumb, Wm, bm, feat);
    // 1280 big-image blocks + 32 thumb blocks
    conv_att_kernel<<<1312, 256, 0, stream>>>(x, thumb, feat, out);
}

// Round 4
// 114.707 us; speedup vs baseline: 1.3582x; 1.3582x over previous
//
#include <hip/hip_runtime.h>

// ---------------------------------------------------------------------------
// Per-batch dynamic conv stack + polynomial attention (f32).
//   feature (8,360) = mean(thumb,(2,3)) @ Wm + bm
//   conv_stack: residual + [3x conv3x3(SAME,leaky 0.2)] -> [5x conv1x1(leaky)]
//   attention:  out = y * (1 + prod_i(a*h + b*w + c*y + d)) per channel
// Outputs: x_out (8,3,512,512) then thumb_out (8,3,64,64), flat f32.
//
// R11 = R9 (proven 44.7us: 16x64 tiles, 256 thr, in-place LDS, STRD=84,
// residual in regs, aligned stores) + phase-aligned lane->quad remap ONLY.
//   * R10 lesson: 120-col tiles + global residual tripled HBM traffic
//     (WRITE 25->91MB, no write coalescing) -> memory-bound 84us. R9's
//     aligned 64-col layout is load-bearing. Reverted wholesale.
//   * Conflict source in R9: 18-quad strips (strip=tid/18) make 3 of 4
//     16-lane LDS phases mix two rows. conv3/residual/epilogue (tid&15)
//     were already clean.
//   * Remap conv1/conv2/stage0: main units s=tid>>4, gx=4*(tid&15) ->
//     every 16-lane phase reads/writes 16 contiguous quads of one row.
//     Halo quads (gx=-4, 64; 2/strip) go to spare wave-2 lanes: conv1
//     160+20 of 180, conv2 144+18 of 162 -> same wave counts, no extra ops.
//   * stage0 main loop now does 64B-aligned full interior rows (better
//     global coalescing too); edge quads in a 132-thread side loop.
// ---------------------------------------------------------------------------

#define LEAKY(v) fmaxf((v), 0.2f * (v))

constexpr int STRD = 84;            // dwords per buffered row (quads 0..17 used,
                                    // dwords 72..83 pad)
constexpr int ROWS0 = 22;           // rows -3..18
constexpr int CHS  = ROWS0 * STRD;  // 1848 dwords per channel slab
constexpr int BUFSZ = 3 * CHS + 16; // 22.2KB

__global__ __launch_bounds__(384) void prep_kernel(
    const float* __restrict__ thumb, const float* __restrict__ Wm,
    const float* __restrict__ bm, float* __restrict__ feat)
{
    const int b = blockIdx.x;                // 8 blocks
    const int t = threadIdx.x;               // 384
    const int ch = t >> 7;                   // 0..2
    const int l  = t & 127;
    const float4* p = (const float4*)(thumb + (size_t)b * 3 * 4096);
    float s = 0.f;
#pragma unroll
    for (int k = 0; k < 8; ++k) {
        float4 v = p[ch * 1024 + l + k * 128];
        s += v.x + v.y + v.z + v.w;
    }
    __shared__ float red[384];
    red[t] = s;
    __syncthreads();
    for (int off = 64; off > 0; off >>= 1) {
        if (l < off) red[t] += red[t + off];
        __syncthreads();
    }
    if (t < 360) {
        const float sc = 1.f / 4096.f;
        const float m0 = red[0] * sc, m1 = red[128] * sc, m2 = red[256] * sc;
        feat[b * 360 + t] =
            fmaf(m0, Wm[t], fmaf(m1, Wm[360 + t], fmaf(m2, Wm[720 + t], bm[t])));
    }
}

// 3x3 conv over a strip of R output rows x 4 cols (gx..gx+3 image cols of
// this tile), all 3 och. fw: 84 uniform weights; r0: first output row;
// gx: first col (multiple of 4; may be -4: left-edge A-clamp feeds only
// discarded outputs). Reads A at gx (buffer), B at gx+4, C at gx+8.
template<int R>
__device__ __forceinline__ void conv_rows(
    const float* __restrict__ buf, const float* __restrict__ fw,
    int r0, int gx, float4 acc[][3])
{
    const float b0 = fw[81], b1 = fw[82], b2 = fw[83];
#pragma unroll
    for (int j = 0; j < R; ++j) {
        acc[j][0] = make_float4(b0, b0, b0, b0);
        acc[j][1] = make_float4(b1, b1, b1, b1);
        acc[j][2] = make_float4(b2, b2, b2, b2);
    }
    const int gA = (gx < 0) ? 0 : gx;
#pragma unroll
    for (int ich = 0; ich < 3; ++ich) {
#pragma unroll
        for (int ri = 0; ri < R + 2; ++ri) {
            const int idx = ich * CHS + (r0 + 2 + ri) * STRD;
            const float4 A = *(const float4*)&buf[idx + gA];     // gx-4..gx-1
            const float4 B = *(const float4*)&buf[idx + gx + 4]; // gx..gx+3
            const float4 C = *(const float4*)&buf[idx + gx + 8]; // gx+4..gx+7
#pragma unroll
            for (int j = 0; j < R; ++j) {
                const int dy = ri - j;
                if (dy < 0 || dy > 2) continue;
#pragma unroll
                for (int oc = 0; oc < 3; ++oc) {
                    const float w0 = fw[oc * 27 + ich * 9 + dy * 3 + 0];
                    const float w1 = fw[oc * 27 + ich * 9 + dy * 3 + 1];
                    const float w2 = fw[oc * 27 + ich * 9 + dy * 3 + 2];
                    float4& a = acc[j][oc];
                    a.x = fmaf(A.w, w0, fmaf(B.x, w1, fmaf(B.y, w2, a.x)));
                    a.y = fmaf(B.x, w0, fmaf(B.y, w1, fmaf(B.z, w2, a.y)));
                    a.z = fmaf(B.y, w0, fmaf(B.z, w1, fmaf(B.w, w2, a.z)));
                    a.w = fmaf(B.z, w0, fmaf(B.w, w1, fmaf(C.x, w2, a.w)));
                }
            }
        }
    }
}

__global__ __launch_bounds__(256, 4) void conv_att_kernel(
    const float* __restrict__ x, const float* __restrict__ thumb,
    const float* __restrict__ feat, float* __restrict__ out)
{
    __shared__ float buf[BUFSZ];

    int id = blockIdx.x;
    const float* src; float* dst; int H, W, b, trow, tcol;
    if (id < 2048) {                 // big: 8 batches x (32 row x 8 col) tiles
        b = id >> 8; const int t = id & 255;
        H = 512; W = 512; trow = (t >> 3) * 16; tcol = (t & 7) * 64;
        src = x; dst = out;
    } else {                         // thumb: 8 batches x 4 row tiles
        const int i2 = id - 2048;
        b = i2 >> 2; trow = (i2 & 3) * 16; tcol = 0;
        H = 64; W = 64; src = thumb;
        dst = out + (size_t)8 * 3 * 512 * 512;
    }
    const float* fb = feat + b * 360;    // uniform -> scalar loads
    const int tid = threadIdx.x;

    // ---- stage0 main: 3ch x 22 rows x 16 interior quads (idx 1..16) ----
    // Phase-aligned in LDS AND 64B-aligned contiguous in global.
    const float* sbg = src + (size_t)b * 3 * H * W;
    for (int q = tid; q < 1056; q += 256) {
        const int c = q / 352;                 // 352 = 22*16
        const int rem = q - c * 352;
        const int mr = rem >> 4;
        const int k  = rem & 15;               // interior quad 0..15
        const int gr = trow + mr - 3;
        const int gc0 = tcol + 4 * k;          // always in [0, W-4]
        float4 v = make_float4(0.f, 0.f, 0.f, 0.f);
        if ((unsigned)gr < (unsigned)H)
            v = *(const float4*)&sbg[(size_t)c * H * W + (size_t)gr * W + gc0];
        *(float4*)&buf[c * CHS + mr * STRD + 4 * (k + 1)] = v;
    }
    // ---- stage0 halo: quads 0 (col tcol-4) and 17 (col tcol+64), 132 units
    if (tid < 132) {
        const int c = tid / 44;                // 44 = 22*2
        const int rem = tid - c * 44;
        const int mr = rem >> 1;
        const int side = rem & 1;
        const int gr = trow + mr - 3;
        const int gc0 = tcol + (side ? 64 : -4);
        const bool rok = (unsigned)gr < (unsigned)H;
        const float* gp = sbg + (size_t)c * H * W + (size_t)(rok ? gr : 0) * W;
        float4 v;
        if (rok && (unsigned)gc0 <= (unsigned)(W - 4)) {
            v = *(const float4*)&gp[gc0];
        } else {
            v.x = (rok && (unsigned)(gc0 + 0) < (unsigned)W) ? gp[gc0 + 0] : 0.f;
            v.y = (rok && (unsigned)(gc0 + 1) < (unsigned)W) ? gp[gc0 + 1] : 0.f;
            v.z = (rok && (unsigned)(gc0 + 2) < (unsigned)W) ? gp[gc0 + 2] : 0.f;
            v.w = (rok && (unsigned)(gc0 + 3) < (unsigned)W) ? gp[gc0 + 3] : 0.f;
        }
        *(float4*)&buf[c * CHS + mr * STRD + (side ? 68 : 0)] = v;
    }
    // zero the pad quad (dwords 72-75): only edge C-reads (gx=64) touch it,
    // feeding discarded col-67 outputs — keep values defined.
    if (tid < 66) {
        const int c = tid / 22, mr = tid - c * 22;
        *(float4*)&buf[c * CHS + mr * STRD + 72] = make_float4(0.f, 0.f, 0.f, 0.f);
    }
    __syncthreads();

    // conv3/output mapping (also residual): 16 rows x 16 quad-groups, R=1
    const int s3 = tid >> 4;             // output row 0..15
    const int gx3 = 4 * (tid & 15);      // output col group

    // ---- conv1: 10 strips (R=2, rows -2..17) x 18 quads = 180 units ----
    // main: 160 units phase-aligned (s=tid>>4, gx=4*(tid&15));
    // halo: 20 units (gx=-4,64) on spare wave-2 lanes. Same wave count as
    // strip=tid/18 mapping, but 2 of 3 waves fully conflict-clean.
    const bool act1 = tid < 180;
    int s1, gx1;
    if (tid < 160) { s1 = tid >> 4; gx1 = 4 * (tid & 15); }
    else { const int v = tid - 160; s1 = v >> 1; gx1 = (v & 1) ? 64 : -4; }
    float4 acc[2][3];
    if (act1) conv_rows<2>(buf, fb, 2 * s1 - 2, gx1, acc);

    // residual stash (stage0 center rows 3..18, read before overwrite)
    float4 res[3];
#pragma unroll
    for (int c = 0; c < 3; ++c)
        res[c] = *(const float4*)&buf[c * CHS + (s3 + 3) * STRD + gx3 + 4];
    __syncthreads();

    if (act1) {
        const int r0 = 2 * s1 - 2;
#pragma unroll
        for (int j = 0; j < 2; ++j)
#pragma unroll
            for (int oc = 0; oc < 3; ++oc) {
                float4 v = acc[j][oc];
                v.x = LEAKY(v.x); v.y = LEAKY(v.y); v.z = LEAKY(v.z); v.w = LEAKY(v.w);
                *(float4*)&buf[oc * CHS + (r0 + j + 3) * STRD + gx1 + 4] = v;
            }
    }
    __syncthreads();

    // ---- conv2: 9 strips (R=2, rows -1..16) x 18 quads = 162 units ----
    const bool act2 = tid < 162;
    int s2, gx2;
    if (tid < 144) { s2 = tid >> 4; gx2 = 4 * (tid & 15); }
    else { const int v = tid - 144; s2 = v >> 1; gx2 = (v & 1) ? 64 : -4; }
    if (act2) conv_rows<2>(buf, fb + 84, 2 * s2 - 1, gx2, acc);
    __syncthreads();

    if (act2) {
        const int r0 = 2 * s2 - 1;
#pragma unroll
        for (int j = 0; j < 2; ++j)
#pragma unroll
            for (int oc = 0; oc < 3; ++oc) {
                float4 v = acc[j][oc];
                v.x = LEAKY(v.x); v.y = LEAKY(v.y); v.z = LEAKY(v.z); v.w = LEAKY(v.w);
                *(float4*)&buf[oc * CHS + (r0 + j + 3) * STRD + gx2 + 4] = v;
            }
    }
    __syncthreads();

    // conv3: rows 0..15, R=1, all 256 threads (already phase-aligned)
    float4 y[1][3];
    conv_rows<1>(buf, fb + 168, s3, gx3, y);
    float4 y0 = y[0][0], y1 = y[0][1], y2 = y[0][2];
    y0.x = LEAKY(y0.x); y0.y = LEAKY(y0.y); y0.z = LEAKY(y0.z); y0.w = LEAKY(y0.w);
    y1.x = LEAKY(y1.x); y1.y = LEAKY(y1.y); y1.z = LEAKY(y1.z); y1.w = LEAKY(y1.w);
    y2.x = LEAKY(y2.x); y2.y = LEAKY(y2.y); y2.z = LEAKY(y2.z); y2.w = LEAKY(y2.w);

    // ---- 5x conv1x1 chain in registers ----
#pragma unroll
    for (int lay = 0; lay < 5; ++lay) {
        const float* fw = fb + 252 + lay * 12;
        const float w00 = fw[0], w01 = fw[1], w02 = fw[2];
        const float w10 = fw[3], w11 = fw[4], w12 = fw[5];
        const float w20 = fw[6], w21 = fw[7], w22 = fw[8];
        const float c0 = fw[9], c1 = fw[10], c2 = fw[11];
        float4 z0, z1, z2;
        z0.x = fmaf(y0.x, w00, fmaf(y1.x, w01, fmaf(y2.x, w02, c0)));
        z0.y = fmaf(y0.y, w00, fmaf(y1.y, w01, fmaf(y2.y, w02, c0)));
        z0.z = fmaf(y0.z, w00, fmaf(y1.z, w01, fmaf(y2.z, w02, c0)));
        z0.w = fmaf(y0.w, w00, fmaf(y1.w, w01, fmaf(y2.w, w02, c0)));
        z1.x = fmaf(y0.x, w10, fmaf(y1.x, w11, fmaf(y2.x, w12, c1)));
        z1.y = fmaf(y0.y, w10, fmaf(y1.y, w11, fmaf(y2.y, w12, c1)));
        z1.z = fmaf(y0.z, w10, fmaf(y1.z, w11, fmaf(y2.z, w12, c1)));
        z1.w = fmaf(y0.w, w10, fmaf(y1.w, w11, fmaf(y2.w, w12, c1)));
        z2.x = fmaf(y0.x, w20, fmaf(y1.x, w21, fmaf(y2.x, w22, c2)));
        z2.y = fmaf(y0.y, w20, fmaf(y1.y, w21, fmaf(y2.y, w22, c2)));
        z2.z = fmaf(y0.z, w20, fmaf(y1.z, w21, fmaf(y2.z, w22, c2)));
        z2.w = fmaf(y0.w, w20, fmaf(y1.w, w21, fmaf(y2.w, w22, c2)));
        y0.x = LEAKY(z0.x); y0.y = LEAKY(z0.y); y0.z = LEAKY(z0.z); y0.w = LEAKY(z0.w);
        y1.x = LEAKY(z1.x); y1.y = LEAKY(z1.y); y1.z = LEAKY(z1.z); y1.w = LEAKY(z1.w);
        y2.x = LEAKY(z2.x); y2.y = LEAKY(z2.y); y2.z = LEAKY(z2.z); y2.w = LEAKY(z2.w);
    }

    // ---- residual + attention + float4 store (1 row x 4 cols x 3 ch) ----
    const float invH = 1.f / (float)H;
    const float invW = 1.f / (float)W;
    const int gr = trow + s3;
    const float h = (float)gr * invH;
    const float wbase = (float)(tcol + gx3) * invW;
    const float4 wv = make_float4(wbase, wbase + invW, wbase + 2.f * invW, wbase + 3.f * invW);
#pragma unroll
    for (int ch = 0; ch < 3; ++ch) {
        const float* fp = fb + 312 + ch * 16;
        const float pa0 = fp[0], pb0 = fp[1], pc0 = fp[2], pd0 = fp[3];
        const float pa1 = fp[4], pb1 = fp[5], pc1 = fp[6], pd1 = fp[7];
        const float pa2 = fp[8], pb2 = fp[9], pc2 = fp[10], pd2 = fp[11];
        const float pa3 = fp[12], pb3 = fp[13], pc3 = fp[14], pd3 = fp[15];
        const float4 yv = (ch == 0) ? y0 : (ch == 1) ? y1 : y2;
        float4 v;
        v.x = yv.x + res[ch].x;
        v.y = yv.y + res[ch].y;
        v.z = yv.z + res[ch].z;
        v.w = yv.w + res[ch].w;
        const float t0 = fmaf(pa0, h, pd0), t1 = fmaf(pa1, h, pd1);
        const float t2 = fmaf(pa2, h, pd2), t3 = fmaf(pa3, h, pd3);
        float4 o;
        float a0 = fmaf(pb0, wv.x, fmaf(pc0, v.x, t0));
        a0 *= fmaf(pb1, wv.x, fmaf(pc1, v.x, t1));
        a0 *= fmaf(pb2, wv.x, fmaf(pc2, v.x, t2));
        a0 *= fmaf(pb3, wv.x, fmaf(pc3, v.x, t3));
        o.x = v.x * (1.f + a0);
        float a1 = fmaf(pb0, wv.y, fmaf(pc0, v.y, t0));
        a1 *= fmaf(pb1, wv.y, fmaf(pc1, v.y, t1));
        a1 *= fmaf(pb2, wv.y, fmaf(pc2, v.y, t2));
        a1 *= fmaf(pb3, wv.y, fmaf(pc3, v.y, t3));
        o.y = v.y * (1.f + a1);
        float a2 = fmaf(pb0, wv.z, fmaf(pc0, v.z, t0));
        a2 *= fmaf(pb1, wv.z, fmaf(pc1, v.z, t1));
        a2 *= fmaf(pb2, wv.z, fmaf(pc2, v.z, t2));
        a2 *= fmaf(pb3, wv.z, fmaf(pc3, v.z, t3));
        o.z = v.z * (1.f + a2);
        float a3 = fmaf(pb0, wv.w, fmaf(pc0, v.w, t0));
        a3 *= fmaf(pb1, wv.w, fmaf(pc1, v.w, t1));
        a3 *= fmaf(pb2, wv.w, fmaf(pc2, v.w, t2));
        a3 *= fmaf(pb3, wv.w, fmaf(pc3, v.w, t3));
        o.w = v.w * (1.f + a3);
        *(float4*)&dst[((size_t)(b * 3 + ch) * H + gr) * W + tcol + gx3] = o;
    }
}

extern "C" void kernel_launch(void* const* d_in, const int* in_sizes, int n_in,
                              void* d_out, int out_size, void* d_ws, size_t ws_size,
                              hipStream_t stream) {
    const float* x = (const float*)d_in[0];       // (8,3,512,512)
    const float* thumb = (const float*)d_in[1];   // (8,3,64,64)
    const float* Wm = (const float*)d_in[2];      // (3,360)
    const float* bm = (const float*)d_in[3];      // (360,)
    float* out = (float*)d_out;
    float* feat = (float*)d_ws;                   // (8,360)

    prep_kernel<<<8, 384, 0, stream>>>(thumb, Wm, bm, feat);
    // 2048 big-image blocks + 32 thumb blocks
    conv_att_kernel<<<2080, 256, 0, stream>>>(x, thumb, feat, out);
}

// Round 5
// 111.813 us; speedup vs baseline: 1.3934x; 1.0259x over previous
//
#include <hip/hip_runtime.h>

// ---------------------------------------------------------------------------
// Per-batch dynamic conv stack + polynomial attention (f32).
//   feature (8,360) = mean(thumb,(2,3)) @ Wm + bm
//   conv_stack: residual + [3x conv3x3(SAME,leaky 0.2)] -> [5x conv1x1(leaky)]
//   attention:  out = y * (1 + prod_i(a*h + b*w + c*y + d)) per channel
// Outputs: x_out (8,3,512,512) then thumb_out (8,3,64,64), flat f32.
//
// R12 = R11 structure (16x64 tiles, 256 thr, in-place LDS, STRD=84) with
// packed-FP32 math (v_pk_fma_f32 via float ext_vector_type(2)):
//   * Evidence: time tracks instruction count (R7->R9), no pipe saturated,
//     conflicts (6-8M) invariant to 3 rounds of layout surgery -> cut
//     instructions, stop touching layout.
//   * Pack along the ROW PAIR of each R=2 strip: conv taps have no x-shift
//     misalignment; vertical input pairs {r,r+1} cost a few movs; weights
//     are SGPR-uniform (op_sel broadcast).
//   * conv3 restructured to 8 R=2 strips on tid<128 (was 16 R=1 rows on
//     256): 2 waves x pk ~= half the issue of 4 waves x scalar; chain +
//     residual + attention epilogue stay packed (pairs already adjacent).
//   * Per-block wave-instrs ~9.2k -> ~6.5k (-29%).
// ---------------------------------------------------------------------------

typedef float v2f __attribute__((ext_vector_type(2)));
#define FMA2(a, b, c) __builtin_elementwise_fma((a), (b), (c))

__device__ __forceinline__ v2f leaky2(v2f v) {
    return __builtin_elementwise_max(v, v * 0.2f);
}

constexpr int STRD = 84;            // dwords per buffered row (quads 0..17 used)
constexpr int ROWS0 = 22;           // rows -3..18
constexpr int CHS  = ROWS0 * STRD;  // 1848 dwords per channel slab
constexpr int BUFSZ = 3 * CHS + 16; // 22.2KB

__global__ __launch_bounds__(384) void prep_kernel(
    const float* __restrict__ thumb, const float* __restrict__ Wm,
    const float* __restrict__ bm, float* __restrict__ feat)
{
    const int b = blockIdx.x;                // 8 blocks
    const int t = threadIdx.x;               // 384
    const int ch = t >> 7;                   // 0..2
    const int l  = t & 127;
    const float4* p = (const float4*)(thumb + (size_t)b * 3 * 4096);
    float s = 0.f;
#pragma unroll
    for (int k = 0; k < 8; ++k) {
        float4 v = p[ch * 1024 + l + k * 128];
        s += v.x + v.y + v.z + v.w;
    }
    __shared__ float red[384];
    red[t] = s;
    __syncthreads();
    for (int off = 64; off > 0; off >>= 1) {
        if (l < off) red[t] += red[t + off];
        __syncthreads();
    }
    if (t < 360) {
        const float sc = 1.f / 4096.f;
        const float m0 = red[0] * sc, m1 = red[128] * sc, m2 = red[256] * sc;
        feat[b * 360 + t] =
            fmaf(m0, Wm[t], fmaf(m1, Wm[360 + t], fmaf(m2, Wm[720 + t], bm[t])));
    }
}

// Packed 3x3 conv over a strip of 2 output rows x 4 cols, all 3 och.
// acc[oc][c] = (row r0, row r0+1) packed. gx: first output col (mult of 4,
// may be -4: A-clamp feeds only discarded outputs).
__device__ __forceinline__ void conv_rows_pk(
    const float* __restrict__ buf, const float* __restrict__ fw,
    int r0, int gx, v2f acc[3][4])
{
    const float b0 = fw[81], b1 = fw[82], b2 = fw[83];
#pragma unroll
    for (int c = 0; c < 4; ++c) {
        v2f i0 = {b0, b0}; v2f i1 = {b1, b1}; v2f i2 = {b2, b2};
        acc[0][c] = i0; acc[1][c] = i1; acc[2][c] = i2;
    }
    const int gA = (gx < 0) ? 0 : gx;
#pragma unroll
    for (int ich = 0; ich < 3; ++ich) {
        float4 QA[4], QB[4], QC[4];
#pragma unroll
        for (int ri = 0; ri < 4; ++ri) {
            const int idx = ich * CHS + (r0 + 2 + ri) * STRD;
            QA[ri] = *(const float4*)&buf[idx + gA];     // only .w consumed
            QB[ri] = *(const float4*)&buf[idx + gx + 4];
            QC[ri] = *(const float4*)&buf[idx + gx + 8]; // only .x consumed
        }
#pragma unroll
        for (int dy = 0; dy < 3; ++dy) {
            // vertical pairs: rows (dy, dy+1) feed output rows (r0, r0+1)
            v2f win[6];
            {
                v2f a = {QA[dy].w, QA[dy + 1].w}; win[0] = a;
                v2f b = {QB[dy].x, QB[dy + 1].x}; win[1] = b;
                v2f c = {QB[dy].y, QB[dy + 1].y}; win[2] = c;
                v2f d = {QB[dy].z, QB[dy + 1].z}; win[3] = d;
                v2f e = {QB[dy].w, QB[dy + 1].w}; win[4] = e;
                v2f f = {QC[dy].x, QC[dy + 1].x}; win[5] = f;
            }
#pragma unroll
            for (int oc = 0; oc < 3; ++oc) {
                const float w0 = fw[oc * 27 + ich * 9 + dy * 3 + 0];
                const float w1 = fw[oc * 27 + ich * 9 + dy * 3 + 1];
                const float w2 = fw[oc * 27 + ich * 9 + dy * 3 + 2];
                v2f W0 = {w0, w0}; v2f W1 = {w1, w1}; v2f W2 = {w2, w2};
#pragma unroll
                for (int c = 0; c < 4; ++c) {
                    acc[oc][c] = FMA2(win[c], W0,
                                 FMA2(win[c + 1], W1,
                                 FMA2(win[c + 2], W2, acc[oc][c])));
                }
            }
        }
    }
}

__device__ __forceinline__ void write_strip_pk(
    float* __restrict__ buf, int r0, int gx, v2f acc[3][4])
{
#pragma unroll
    for (int oc = 0; oc < 3; ++oc) {
        v2f l0 = leaky2(acc[oc][0]);
        v2f l1 = leaky2(acc[oc][1]);
        v2f l2 = leaky2(acc[oc][2]);
        v2f l3 = leaky2(acc[oc][3]);
        float4 ra = make_float4(l0.x, l1.x, l2.x, l3.x);
        float4 rb = make_float4(l0.y, l1.y, l2.y, l3.y);
        *(float4*)&buf[oc * CHS + (r0 + 3) * STRD + gx + 4] = ra;
        *(float4*)&buf[oc * CHS + (r0 + 4) * STRD + gx + 4] = rb;
    }
}

__global__ __launch_bounds__(256, 4) void conv_att_kernel(
    const float* __restrict__ x, const float* __restrict__ thumb,
    const float* __restrict__ feat, float* __restrict__ out)
{
    __shared__ float buf[BUFSZ];

    int id = blockIdx.x;
    const float* src; float* dst; int H, W, b, trow, tcol;
    if (id < 2048) {                 // big: 8 batches x (32 row x 8 col) tiles
        b = id >> 8; const int t = id & 255;
        H = 512; W = 512; trow = (t >> 3) * 16; tcol = (t & 7) * 64;
        src = x; dst = out;
    } else {                         // thumb: 8 batches x 4 row tiles
        const int i2 = id - 2048;
        b = i2 >> 2; trow = (i2 & 3) * 16; tcol = 0;
        H = 64; W = 64; src = thumb;
        dst = out + (size_t)8 * 3 * 512 * 512;
    }
    const float* fb = feat + b * 360;    // uniform -> scalar loads
    const int tid = threadIdx.x;

    // ---- stage0 main: 3ch x 22 rows x 16 interior quads (idx 1..16) ----
    const float* sbg = src + (size_t)b * 3 * H * W;
    for (int q = tid; q < 1056; q += 256) {
        const int c = q / 352;                 // 352 = 22*16
        const int rem = q - c * 352;
        const int mr = rem >> 4;
        const int k  = rem & 15;               // interior quad 0..15
        const int gr = trow + mr - 3;
        const int gc0 = tcol + 4 * k;          // always in [0, W-4]
        float4 v = make_float4(0.f, 0.f, 0.f, 0.f);
        if ((unsigned)gr < (unsigned)H)
            v = *(const float4*)&sbg[(size_t)c * H * W + (size_t)gr * W + gc0];
        *(float4*)&buf[c * CHS + mr * STRD + 4 * (k + 1)] = v;
    }
    // ---- stage0 halo: quads 0 (col tcol-4) and 17 (col tcol+64), 132 units
    if (tid < 132) {
        const int c = tid / 44;                // 44 = 22*2
        const int rem = tid - c * 44;
        const int mr = rem >> 1;
        const int side = rem & 1;
        const int gr = trow + mr - 3;
        const int gc0 = tcol + (side ? 64 : -4);
        const bool rok = (unsigned)gr < (unsigned)H;
        const float* gp = sbg + (size_t)c * H * W + (size_t)(rok ? gr : 0) * W;
        float4 v;
        if (rok && (unsigned)gc0 <= (unsigned)(W - 4)) {
            v = *(const float4*)&gp[gc0];
        } else {
            v.x = (rok && (unsigned)(gc0 + 0) < (unsigned)W) ? gp[gc0 + 0] : 0.f;
            v.y = (rok && (unsigned)(gc0 + 1) < (unsigned)W) ? gp[gc0 + 1] : 0.f;
            v.z = (rok && (unsigned)(gc0 + 2) < (unsigned)W) ? gp[gc0 + 2] : 0.f;
            v.w = (rok && (unsigned)(gc0 + 3) < (unsigned)W) ? gp[gc0 + 3] : 0.f;
        }
        *(float4*)&buf[c * CHS + mr * STRD + (side ? 68 : 0)] = v;
    }
    // zero the pad quad (dwords 72-75): only edge C-reads (gx=64) touch it,
    // feeding discarded col-67 outputs — keep values defined.
    if (tid < 66) {
        const int c = tid / 22, mr = tid - c * 22;
        *(float4*)&buf[c * CHS + mr * STRD + 72] = make_float4(0.f, 0.f, 0.f, 0.f);
    }
    __syncthreads();

    // ---- conv1: 10 strips (R=2, rows -2..17) x 18 quads = 180 units ----
    // main: 160 units (s=tid>>4, gx=4*(tid&15)); halo: 20 on lanes 160-179.
    const bool act1 = tid < 180;
    int s1, gx1;
    if (tid < 160) { s1 = tid >> 4; gx1 = 4 * (tid & 15); }
    else { const int v = tid - 160; s1 = v >> 1; gx1 = (v & 1) ? 64 : -4; }
    v2f acc[3][4];
    if (act1) conv_rows_pk(buf, fb, 2 * s1 - 2, gx1, acc);

    // ---- residual stash: tid<128 owns output strip (rows 2s3, 2s3+1) ----
    const int s3 = tid >> 4;             // strip 0..7 (valid for tid<128)
    const int gx3 = 4 * (tid & 15);
    v2f res2[3][4];
    if (tid < 128) {
#pragma unroll
        for (int ch = 0; ch < 3; ++ch) {
            float4 ra = *(const float4*)&buf[ch * CHS + (2 * s3 + 3) * STRD + gx3 + 4];
            float4 rb = *(const float4*)&buf[ch * CHS + (2 * s3 + 4) * STRD + gx3 + 4];
            v2f p0 = {ra.x, rb.x}; res2[ch][0] = p0;
            v2f p1 = {ra.y, rb.y}; res2[ch][1] = p1;
            v2f p2 = {ra.z, rb.z}; res2[ch][2] = p2;
            v2f p3 = {ra.w, rb.w}; res2[ch][3] = p3;
        }
    }
    __syncthreads();

    if (act1) write_strip_pk(buf, 2 * s1 - 2, gx1, acc);
    __syncthreads();

    // ---- conv2: 9 strips (R=2, rows -1..16) x 18 quads = 162 units ----
    const bool act2 = tid < 162;
    int s2, gx2;
    if (tid < 144) { s2 = tid >> 4; gx2 = 4 * (tid & 15); }
    else { const int v = tid - 144; s2 = v >> 1; gx2 = (v & 1) ? 64 : -4; }
    if (act2) conv_rows_pk(buf, fb + 84, 2 * s2 - 1, gx2, acc);
    __syncthreads();

    if (act2) write_strip_pk(buf, 2 * s2 - 1, gx2, acc);
    __syncthreads();

    // ---- conv3: 8 strips (R=2, rows 0..15) x 16 quads = 128 units ----
    if (tid < 128) {
        v2f y[3][4];
        {
            v2f acc3[3][4];
            conv_rows_pk(buf, fb + 168, 2 * s3, gx3, acc3);
#pragma unroll
            for (int oc = 0; oc < 3; ++oc)
#pragma unroll
                for (int c = 0; c < 4; ++c) y[oc][c] = leaky2(acc3[oc][c]);
        }

        // ---- 5x conv1x1 chain, packed over the row pair ----
#pragma unroll
        for (int lay = 0; lay < 5; ++lay) {
            const float* fw = fb + 252 + lay * 12;
            v2f W0 = {fw[0], fw[0]}; v2f W1 = {fw[1], fw[1]}; v2f W2 = {fw[2], fw[2]};
            v2f W3 = {fw[3], fw[3]}; v2f W4 = {fw[4], fw[4]}; v2f W5 = {fw[5], fw[5]};
            v2f W6 = {fw[6], fw[6]}; v2f W7 = {fw[7], fw[7]}; v2f W8 = {fw[8], fw[8]};
            v2f C0 = {fw[9], fw[9]}; v2f C1 = {fw[10], fw[10]}; v2f C2 = {fw[11], fw[11]};
            v2f z0[4], z1[4], z2[4];
#pragma unroll
            for (int c = 0; c < 4; ++c) {
                z0[c] = FMA2(y[0][c], W0, FMA2(y[1][c], W1, FMA2(y[2][c], W2, C0)));
                z1[c] = FMA2(y[0][c], W3, FMA2(y[1][c], W4, FMA2(y[2][c], W5, C1)));
                z2[c] = FMA2(y[0][c], W6, FMA2(y[1][c], W7, FMA2(y[2][c], W8, C2)));
            }
#pragma unroll
            for (int c = 0; c < 4; ++c) {
                y[0][c] = leaky2(z0[c]);
                y[1][c] = leaky2(z1[c]);
                y[2][c] = leaky2(z2[c]);
            }
        }

        // ---- residual + attention + store (2 rows x 4 cols x 3 ch) ----
        const float invH = 1.f / (float)H;
        const float invW = 1.f / (float)W;
        const int gr0 = trow + 2 * s3;
        v2f h2 = {(float)gr0 * invH, (float)(gr0 + 1) * invH};
        const float wb = (float)(tcol + gx3) * invW;
        const v2f one = {1.f, 1.f};
#pragma unroll
        for (int ch = 0; ch < 3; ++ch) {
            const float* fp = fb + 312 + ch * 16;
            v2f PA0 = {fp[0], fp[0]},  PB0 = {fp[1], fp[1]},  PC0 = {fp[2], fp[2]},  PD0 = {fp[3], fp[3]};
            v2f PA1 = {fp[4], fp[4]},  PB1 = {fp[5], fp[5]},  PC1 = {fp[6], fp[6]},  PD1 = {fp[7], fp[7]};
            v2f PA2 = {fp[8], fp[8]},  PB2 = {fp[9], fp[9]},  PC2 = {fp[10], fp[10]}, PD2 = {fp[11], fp[11]};
            v2f PA3 = {fp[12], fp[12]}, PB3 = {fp[13], fp[13]}, PC3 = {fp[14], fp[14]}, PD3 = {fp[15], fp[15]};
            v2f t0 = FMA2(PA0, h2, PD0);
            v2f t1 = FMA2(PA1, h2, PD1);
            v2f t2 = FMA2(PA2, h2, PD2);
            v2f t3 = FMA2(PA3, h2, PD3);
            v2f o[4];
#pragma unroll
            for (int c = 0; c < 4; ++c) {
                const float wcs = wb + (float)c * invW;
                v2f Wc = {wcs, wcs};
                v2f v = y[ch][c] + res2[ch][c];
                v2f a = FMA2(PB0, Wc, FMA2(PC0, v, t0));
                a = a * FMA2(PB1, Wc, FMA2(PC1, v, t1));
                a = a * FMA2(PB2, Wc, FMA2(PC2, v, t2));
                a = a * FMA2(PB3, Wc, FMA2(PC3, v, t3));
                o[c] = v * (one + a);
            }
            float4 ra = make_float4(o[0].x, o[1].x, o[2].x, o[3].x);
            float4 rb = make_float4(o[0].y, o[1].y, o[2].y, o[3].y);
            float* dp = &dst[((size_t)(b * 3 + ch) * H + gr0) * W + tcol + gx3];
            *(float4*)dp = ra;
            *(float4*)(dp + W) = rb;
        }
    }
}

extern "C" void kernel_launch(void* const* d_in, const int* in_sizes, int n_in,
                              void* d_out, int out_size, void* d_ws, size_t ws_size,
                              hipStream_t stream) {
    const float* x = (const float*)d_in[0];       // (8,3,512,512)
    const float* thumb = (const float*)d_in[1];   // (8,3,64,64)
    const float* Wm = (const float*)d_in[2];      // (3,360)
    const float* bm = (const float*)d_in[3];      // (360,)
    float* out = (float*)d_out;
    float* feat = (float*)d_ws;                   // (8,360)

    prep_kernel<<<8, 384, 0, stream>>>(thumb, Wm, bm, feat);
    // 2048 big-image blocks + 32 thumb blocks
    conv_att_kernel<<<2080, 256, 0, stream>>>(x, thumb, feat, out);
}

// Round 7
// 111.747 us; speedup vs baseline: 1.3942x; 1.0006x over previous
//
#include <hip/hip_runtime.h>

// ---------------------------------------------------------------------------
// Per-batch dynamic conv stack + polynomial attention (f32).
//   feature (8,360) = mean(thumb,(2,3)) @ Wm + bm
//   conv_stack: residual + [3x conv3x3(SAME,leaky 0.2)] -> [5x conv1x1(leaky)]
//   attention:  out = y * (1 + prod_i(a*h + b*w + c*y + d)) per channel
// Outputs: x_out (8,3,512,512) then thumb_out (8,3,64,64), flat f32.
//
// R14 = R13 resubmitted (round-6 bench was an infra failure: container
// failed at acquire, no compile error, no counters; source re-audited for
// faults — LDS bounds, alignment, races all clean).
//
// R13 = R12 (pk-f32 math, 16x64 tiles, 256 thr) with COLUMN-MAJOR LDS:
//   * R12 lesson: pk over the row pair is right, but row-major LDS makes
//     every v2f operand cost packing movs (~108/unit, ate the FMA savings).
//   * Layout [ch][col][row], row-stride 1: the (r,r+1) pair is adjacent ->
//     8B align-4 load IS the pk operand (ds_read2_b32, zero movs). Conv
//     unit: 54 read2 (432B) vs 36 b128 (576B) + 108 movs; writes store
//     acc pairs directly. Per-unit instrs 252 -> ~162.
//   * CSTR=23: adjacent lanes (cols 4 apart) step 92 = 28 mod 32 banks,
//     period 8 -> 2 lanes/bank (free, m136) for ALL conv reads/writes and
//     stage0 transpose writes. Bank behavior engineered, not modeled.
//   * stage0 transposes each global float4 into 4 scalar LDS writes
//     (latency-dominated phase, negligible). Store path unchanged (R10:
//     aligned 64-col global writes are load-bearing).
//   * LDS 19.7KB (8 blocks/CU by LDS), (256,4) -> VGPR<=128.
// ---------------------------------------------------------------------------

typedef float v2f __attribute__((ext_vector_type(2)));
#define FMA2(a, b, c) __builtin_elementwise_fma((a), (b), (c))

__device__ __forceinline__ v2f leaky2(v2f v) {
    return __builtin_elementwise_max(v, v * 0.2f);
}

// align-4 LDS pair load/store: compiles to ds_read2_b32 / ds_write2_b32
__device__ __forceinline__ v2f ldpair(const float* p) {
    v2f r; __builtin_memcpy(&r, p, 8); return r;
}
__device__ __forceinline__ void stpair(float* p, v2f v) {
    __builtin_memcpy(p, &v, 8);
}

constexpr int ROWS0 = 22;           // rows -3..18 of the 16-row tile
constexpr int NCOLS = 73;           // cols -4..67 + zero pad col 72
constexpr int CSTR  = 23;           // col stride (rows 0..21 + 1 pad); 4*23=92=28 mod 32
constexpr int CHS   = NCOLS * CSTR; // 1679 dwords per channel slab
constexpr int BUFSZ = 3 * CHS + 4;  // 19.7KB

__global__ __launch_bounds__(384) void prep_kernel(
    const float* __restrict__ thumb, const float* __restrict__ Wm,
    const float* __restrict__ bm, float* __restrict__ feat)
{
    const int b = blockIdx.x;                // 8 blocks
    const int t = threadIdx.x;               // 384
    const int ch = t >> 7;                   // 0..2
    const int l  = t & 127;
    const float4* p = (const float4*)(thumb + (size_t)b * 3 * 4096);
    float s = 0.f;
#pragma unroll
    for (int k = 0; k < 8; ++k) {
        float4 v = p[ch * 1024 + l + k * 128];
        s += v.x + v.y + v.z + v.w;
    }
    __shared__ float red[384];
    red[t] = s;
    __syncthreads();
    for (int off = 64; off > 0; off >>= 1) {
        if (l < off) red[t] += red[t + off];
        __syncthreads();
    }
    if (t < 360) {
        const float sc = 1.f / 4096.f;
        const float m0 = red[0] * sc, m1 = red[128] * sc, m2 = red[256] * sc;
        feat[b * 360 + t] =
            fmaf(m0, Wm[t], fmaf(m1, Wm[360 + t], fmaf(m2, Wm[720 + t], bm[t])));
    }
}

// Packed 3x3 conv over a strip of 2 output rows x 4 cols, all 3 och.
// acc[oc][c] = (row r0, row r0+1) packed. Col-major buffer: window col
// w (0..5) = buffer col gx+3+w (image col gx+c-1 for output col c uses
// w=c..c+2). gx may be -4 (halo): win[0] clamps to col 3, feeding only
// discarded outputs. Tap row pair for dy = buffer rows (r0+2+dy, r0+3+dy).
__device__ __forceinline__ void conv_rows_pk(
    const float* __restrict__ buf, const float* __restrict__ fw,
    int r0, int gx, v2f acc[3][4])
{
    const float b0 = fw[81], b1 = fw[82], b2 = fw[83];
#pragma unroll
    for (int c = 0; c < 4; ++c) {
        v2f i0 = {b0, b0}; v2f i1 = {b1, b1}; v2f i2 = {b2, b2};
        acc[0][c] = i0; acc[1][c] = i1; acc[2][c] = i2;
    }
    const int c0 = (gx < 0) ? 3 : gx + 3;
    const int rb = r0 + 2;
#pragma unroll
    for (int ich = 0; ich < 3; ++ich) {
        const int base = ich * CHS + rb;
#pragma unroll
        for (int dy = 0; dy < 3; ++dy) {
            v2f win[6];
            win[0] = ldpair(&buf[base + c0 * CSTR + dy]);
#pragma unroll
            for (int k = 1; k < 6; ++k)
                win[k] = ldpair(&buf[base + (gx + 3 + k) * CSTR + dy]);
#pragma unroll
            for (int oc = 0; oc < 3; ++oc) {
                const float w0 = fw[oc * 27 + ich * 9 + dy * 3 + 0];
                const float w1 = fw[oc * 27 + ich * 9 + dy * 3 + 1];
                const float w2 = fw[oc * 27 + ich * 9 + dy * 3 + 2];
                v2f W0 = {w0, w0}; v2f W1 = {w1, w1}; v2f W2 = {w2, w2};
#pragma unroll
                for (int c = 0; c < 4; ++c) {
                    acc[oc][c] = FMA2(win[c], W0,
                                 FMA2(win[c + 1], W1,
                                 FMA2(win[c + 2], W2, acc[oc][c])));
                }
            }
        }
    }
}

// Write leaky(acc) pairs to buffer rows (r0+3, r0+4), cols gx+4..gx+7.
__device__ __forceinline__ void write_strip_pk(
    float* __restrict__ buf, int r0, int gx, v2f acc[3][4])
{
#pragma unroll
    for (int oc = 0; oc < 3; ++oc)
#pragma unroll
        for (int c = 0; c < 4; ++c)
            stpair(&buf[oc * CHS + (gx + 4 + c) * CSTR + (r0 + 3)],
                   leaky2(acc[oc][c]));
}

__global__ __launch_bounds__(256, 4) void conv_att_kernel(
    const float* __restrict__ x, const float* __restrict__ thumb,
    const float* __restrict__ feat, float* __restrict__ out)
{
    __shared__ float buf[BUFSZ];

    int id = blockIdx.x;
    const float* src; float* dst; int H, W, b, trow, tcol;
    if (id < 2048) {                 // big: 8 batches x (32 row x 8 col) tiles
        b = id >> 8; const int t = id & 255;
        H = 512; W = 512; trow = (t >> 3) * 16; tcol = (t & 7) * 64;
        src = x; dst = out;
    } else {                         // thumb: 8 batches x 4 row tiles
        const int i2 = id - 2048;
        b = i2 >> 2; trow = (i2 & 3) * 16; tcol = 0;
        H = 64; W = 64; src = thumb;
        dst = out + (size_t)8 * 3 * 512 * 512;
    }
    const float* fb = feat + b * 360;    // uniform -> scalar loads
    const int tid = threadIdx.x;

    // ---- stage0 main: 3ch x 22 rows x 16 interior quads -> transpose ----
    // Global reads stay 64B-aligned coalesced float4; LDS store = 4 scalars
    // at col stride CSTR (2 lanes/bank).
    const float* sbg = src + (size_t)b * 3 * H * W;
    for (int q = tid; q < 1056; q += 256) {
        const int c = q / 352;                 // 352 = 22*16
        const int rem = q - c * 352;
        const int mr = rem >> 4;
        const int k  = rem & 15;               // interior quad 0..15
        const int gr = trow + mr - 3;
        const int gc0 = tcol + 4 * k;          // always in [0, W-4]
        float4 v = make_float4(0.f, 0.f, 0.f, 0.f);
        if ((unsigned)gr < (unsigned)H)
            v = *(const float4*)&sbg[(size_t)c * H * W + (size_t)gr * W + gc0];
        float* bp = &buf[c * CHS + (4 * k + 4) * CSTR + mr];
        bp[0] = v.x; bp[CSTR] = v.y; bp[2 * CSTR] = v.z; bp[3 * CSTR] = v.w;
    }
    // ---- stage0 halo: cols 0..3 (img tcol-4) and 68..71 (img tcol+64) ----
    if (tid < 132) {
        const int c = tid / 44;                // 44 = 22*2
        const int rem = tid - c * 44;
        const int mr = rem >> 1;
        const int side = rem & 1;
        const int gr = trow + mr - 3;
        const int gc0 = tcol + (side ? 64 : -4);
        const bool rok = (unsigned)gr < (unsigned)H;
        const float* gp = sbg + (size_t)c * H * W + (size_t)(rok ? gr : 0) * W;
        float4 v;
        if (rok && (unsigned)gc0 <= (unsigned)(W - 4)) {
            v = *(const float4*)&gp[gc0];
        } else {
            v.x = (rok && (unsigned)(gc0 + 0) < (unsigned)W) ? gp[gc0 + 0] : 0.f;
            v.y = (rok && (unsigned)(gc0 + 1) < (unsigned)W) ? gp[gc0 + 1] : 0.f;
            v.z = (rok && (unsigned)(gc0 + 2) < (unsigned)W) ? gp[gc0 + 2] : 0.f;
            v.w = (rok && (unsigned)(gc0 + 3) < (unsigned)W) ? gp[gc0 + 3] : 0.f;
        }
        float* bp = &buf[c * CHS + (side ? 68 : 0) * CSTR + mr];
        bp[0] = v.x; bp[CSTR] = v.y; bp[2 * CSTR] = v.z; bp[3 * CSTR] = v.w;
    }
    // zero pad col 72: only edge windows (gx=64) read it, feeding discarded
    // col-67 outputs — keep values defined.
    if (tid < 66) {
        const int c = tid / 22, mr = tid - c * 22;
        buf[c * CHS + 72 * CSTR + mr] = 0.f;
    }
    __syncthreads();

    // ---- conv1: 10 strips (R=2, rows -2..17) x 18 quads = 180 units ----
    // main: 160 units (s=tid>>4, gx=4*(tid&15)); halo: 20 on lanes 160-179.
    const bool act1 = tid < 180;
    int s1, gx1;
    if (tid < 160) { s1 = tid >> 4; gx1 = 4 * (tid & 15); }
    else { const int v = tid - 160; s1 = v >> 1; gx1 = (v & 1) ? 64 : -4; }
    v2f acc[3][4];
    if (act1) conv_rows_pk(buf, fb, 2 * s1 - 2, gx1, acc);

    // ---- residual stash: tid<128 owns output strip (rows 2s3, 2s3+1) ----
    const int s3 = tid >> 4;             // strip 0..7 (valid for tid<128)
    const int gx3 = 4 * (tid & 15);
    v2f res2[3][4];
    if (tid < 128) {
#pragma unroll
        for (int ch = 0; ch < 3; ++ch)
#pragma unroll
            for (int c = 0; c < 4; ++c)
                res2[ch][c] = ldpair(&buf[ch * CHS + (gx3 + 4 + c) * CSTR + (2 * s3 + 3)]);
    }
    __syncthreads();

    if (act1) write_strip_pk(buf, 2 * s1 - 2, gx1, acc);
    __syncthreads();

    // ---- conv2: 9 strips (R=2, rows -1..16) x 18 quads = 162 units ----
    const bool act2 = tid < 162;
    int s2, gx2;
    if (tid < 144) { s2 = tid >> 4; gx2 = 4 * (tid & 15); }
    else { const int v = tid - 144; s2 = v >> 1; gx2 = (v & 1) ? 64 : -4; }
    if (act2) conv_rows_pk(buf, fb + 84, 2 * s2 - 1, gx2, acc);
    __syncthreads();

    if (act2) write_strip_pk(buf, 2 * s2 - 1, gx2, acc);
    __syncthreads();

    // ---- conv3: 8 strips (R=2, rows 0..15) x 16 quads = 128 units ----
    if (tid < 128) {
        v2f y[3][4];
        {
            v2f acc3[3][4];
            conv_rows_pk(buf, fb + 168, 2 * s3, gx3, acc3);
#pragma unroll
            for (int oc = 0; oc < 3; ++oc)
#pragma unroll
                for (int c = 0; c < 4; ++c) y[oc][c] = leaky2(acc3[oc][c]);
        }

        // ---- 5x conv1x1 chain, packed over the row pair ----
#pragma unroll
        for (int lay = 0; lay < 5; ++lay) {
            const float* fw = fb + 252 + lay * 12;
            v2f W0 = {fw[0], fw[0]}; v2f W1 = {fw[1], fw[1]}; v2f W2 = {fw[2], fw[2]};
            v2f W3 = {fw[3], fw[3]}; v2f W4 = {fw[4], fw[4]}; v2f W5 = {fw[5], fw[5]};
            v2f W6 = {fw[6], fw[6]}; v2f W7 = {fw[7], fw[7]}; v2f W8 = {fw[8], fw[8]};
            v2f C0 = {fw[9], fw[9]}; v2f C1 = {fw[10], fw[10]}; v2f C2 = {fw[11], fw[11]};
            v2f z0[4], z1[4], z2[4];
#pragma unroll
            for (int c = 0; c < 4; ++c) {
                z0[c] = FMA2(y[0][c], W0, FMA2(y[1][c], W1, FMA2(y[2][c], W2, C0)));
                z1[c] = FMA2(y[0][c], W3, FMA2(y[1][c], W4, FMA2(y[2][c], W5, C1)));
                z2[c] = FMA2(y[0][c], W6, FMA2(y[1][c], W7, FMA2(y[2][c], W8, C2)));
            }
#pragma unroll
            for (int c = 0; c < 4; ++c) {
                y[0][c] = leaky2(z0[c]);
                y[1][c] = leaky2(z1[c]);
                y[2][c] = leaky2(z2[c]);
            }
        }

        // ---- residual + attention + store (2 rows x 4 cols x 3 ch) ----
        const float invH = 1.f / (float)H;
        const float invW = 1.f / (float)W;
        const int gr0 = trow + 2 * s3;
        v2f h2 = {(float)gr0 * invH, (float)(gr0 + 1) * invH};
        const float wb = (float)(tcol + gx3) * invW;
        const v2f one = {1.f, 1.f};
#pragma unroll
        for (int ch = 0; ch < 3; ++ch) {
            const float* fp = fb + 312 + ch * 16;
            v2f PA0 = {fp[0], fp[0]},  PB0 = {fp[1], fp[1]},  PC0 = {fp[2], fp[2]},  PD0 = {fp[3], fp[3]};
            v2f PA1 = {fp[4], fp[4]},  PB1 = {fp[5], fp[5]},  PC1 = {fp[6], fp[6]},  PD1 = {fp[7], fp[7]};
            v2f PA2 = {fp[8], fp[8]},  PB2 = {fp[9], fp[9]},  PC2 = {fp[10], fp[10]}, PD2 = {fp[11], fp[11]};
            v2f PA3 = {fp[12], fp[12]}, PB3 = {fp[13], fp[13]}, PC3 = {fp[14], fp[14]}, PD3 = {fp[15], fp[15]};
            v2f t0 = FMA2(PA0, h2, PD0);
            v2f t1 = FMA2(PA1, h2, PD1);
            v2f t2 = FMA2(PA2, h2, PD2);
            v2f t3 = FMA2(PA3, h2, PD3);
            v2f o[4];
#pragma unroll
            for (int c = 0; c < 4; ++c) {
                const float wcs = wb + (float)c * invW;
                v2f Wc = {wcs, wcs};
                v2f v = y[ch][c] + res2[ch][c];
                v2f a = FMA2(PB0, Wc, FMA2(PC0, v, t0));
                a = a * FMA2(PB1, Wc, FMA2(PC1, v, t1));
                a = a * FMA2(PB2, Wc, FMA2(PC2, v, t2));
                a = a * FMA2(PB3, Wc, FMA2(PC3, v, t3));
                o[c] = v * (one + a);
            }
            float4 ra = make_float4(o[0].x, o[1].x, o[2].x, o[3].x);
            float4 rb = make_float4(o[0].y, o[1].y, o[2].y, o[3].y);
            float* dp = &dst[((size_t)(b * 3 + ch) * H + gr0) * W + tcol + gx3];
            *(float4*)dp = ra;
            *(float4*)(dp + W) = rb;
        }
    }
}

extern "C" void kernel_launch(void* const* d_in, const int* in_sizes, int n_in,
                              void* d_out, int out_size, void* d_ws, size_t ws_size,
                              hipStream_t stream) {
    const float* x = (const float*)d_in[0];       // (8,3,512,512)
    const float* thumb = (const float*)d_in[1];   // (8,3,64,64)
    const float* Wm = (const float*)d_in[2];      // (3,360)
    const float* bm = (const float*)d_in[3];      // (360,)
    float* out = (float*)d_out;
    float* feat = (float*)d_ws;                   // (8,360)

    prep_kernel<<<8, 384, 0, stream>>>(thumb, Wm, bm, feat);
    // 2048 big-image blocks + 32 thumb blocks
    conv_att_kernel<<<2080, 256, 0, stream>>>(x, thumb, feat, out);
}

// Round 8
// 110.317 us; speedup vs baseline: 1.4123x; 1.0130x over previous
//
#include <hip/hip_runtime.h>

// ---------------------------------------------------------------------------
// Per-batch dynamic conv stack + polynomial attention (f32).
//   feature (8,360) = mean(thumb,(2,3)) @ Wm + bm
//   conv_stack: residual + [3x conv3x3(SAME,leaky 0.2)] -> [5x conv1x1(leaky)]
//   attention:  out = y * (1 + prod_i(a*h + b*w + c*y + d)) per channel
// Outputs: x_out (8,3,512,512) then thumb_out (8,3,64,64), flat f32.
//
// R15 = R13 (pk-f32, col-major LDS, 16x64 tiles, 256 thr) + PING-PONG:
//   * R13 finding: VALU 39%, LDS ~31%, ~60% of cycles no pipe issues ->
//     stall-bound (5 barriers serialize in-place read->write phases;
//     stage0 = ~5 dependent global-load rounds on the critical path).
//   * Ping-pong: conv1 A->B, conv2 B->A (input dead after residual stash),
//     conv3 reads A. 3 barriers instead of 5; no read/write hazard inside
//     a phase; no acc live across a barrier.
//   * stage0 split (T14): issue all 5 global loads into regs back-to-back,
//     then write LDS -> one HBM latency instead of ~5 serialized.
//   * Cost: LDS 37.7KB -> 4 blocks/CU cap (measured occupancy ~2.5 blocks,
//     cap should not bind — occupancy counter is the falsifier).
//   * Conflicts: residual 4.6M = 4-lanes/bank floor over wave64 (col-step
//     banks are multiples of 4; strip-step adds even offsets). ~1.58x on
//     LDS pipe, mostly hidden. Not worth further surgery.
// ---------------------------------------------------------------------------

typedef float v2f __attribute__((ext_vector_type(2)));
#define FMA2(a, b, c) __builtin_elementwise_fma((a), (b), (c))

__device__ __forceinline__ v2f leaky2(v2f v) {
    return __builtin_elementwise_max(v, v * 0.2f);
}

// align-4 LDS pair load/store: compiles to ds_read2_b32 / ds_write2_b32
__device__ __forceinline__ v2f ldpair(const float* p) {
    v2f r; __builtin_memcpy(&r, p, 8); return r;
}
__device__ __forceinline__ void stpair(float* p, v2f v) {
    __builtin_memcpy(p, &v, 8);
}

constexpr int NCOLS = 73;            // cols -4..67 + zero pad col 72
constexpr int CSTRA = 23;            // A: input/conv2-out, 22 rows + pad
constexpr int CHSA  = NCOLS * CSTRA; // 1679
constexpr int ASZ   = 3 * CHSA + 4;  // 20.2KB
constexpr int CSTRB = 21;            // B: conv1-out, 20 rows + pad
constexpr int CHSB  = NCOLS * CSTRB; // 1533
constexpr int BSZ   = 3 * CHSB + 4;  // 18.4KB

__global__ __launch_bounds__(384) void prep_kernel(
    const float* __restrict__ thumb, const float* __restrict__ Wm,
    const float* __restrict__ bm, float* __restrict__ feat)
{
    const int b = blockIdx.x;                // 8 blocks
    const int t = threadIdx.x;               // 384
    const int ch = t >> 7;                   // 0..2
    const int l  = t & 127;
    const float4* p = (const float4*)(thumb + (size_t)b * 3 * 4096);
    float s = 0.f;
#pragma unroll
    for (int k = 0; k < 8; ++k) {
        float4 v = p[ch * 1024 + l + k * 128];
        s += v.x + v.y + v.z + v.w;
    }
    __shared__ float red[384];
    red[t] = s;
    __syncthreads();
    for (int off = 64; off > 0; off >>= 1) {
        if (l < off) red[t] += red[t + off];
        __syncthreads();
    }
    if (t < 360) {
        const float sc = 1.f / 4096.f;
        const float m0 = red[0] * sc, m1 = red[128] * sc, m2 = red[256] * sc;
        feat[b * 360 + t] =
            fmaf(m0, Wm[t], fmaf(m1, Wm[360 + t], fmaf(m2, Wm[720 + t], bm[t])));
    }
}

// Packed 3x3 conv over a strip of 2 output rows x 4 cols, all 3 och.
// acc[oc][c] = (row r0, row r0+1) packed. rb = buffer row of the first tap
// pair (taps read rows rb+dy, rb+dy+1 for dy=0..2). gx may be -4 (halo):
// win[0] clamps to col 3, feeding only discarded outputs.
template<int CHS_, int CSTR_>
__device__ __forceinline__ void conv_rows_pk(
    const float* __restrict__ buf, const float* __restrict__ fw,
    int rb, int gx, v2f acc[3][4])
{
    const float b0 = fw[81], b1 = fw[82], b2 = fw[83];
#pragma unroll
    for (int c = 0; c < 4; ++c) {
        v2f i0 = {b0, b0}; v2f i1 = {b1, b1}; v2f i2 = {b2, b2};
        acc[0][c] = i0; acc[1][c] = i1; acc[2][c] = i2;
    }
    const int c0 = (gx < 0) ? 3 : gx + 3;
#pragma unroll
    for (int ich = 0; ich < 3; ++ich) {
        const int base = ich * CHS_ + rb;
#pragma unroll
        for (int dy = 0; dy < 3; ++dy) {
            v2f win[6];
            win[0] = ldpair(&buf[base + c0 * CSTR_ + dy]);
#pragma unroll
            for (int k = 1; k < 6; ++k)
                win[k] = ldpair(&buf[base + (gx + 3 + k) * CSTR_ + dy]);
#pragma unroll
            for (int oc = 0; oc < 3; ++oc) {
                const float w0 = fw[oc * 27 + ich * 9 + dy * 3 + 0];
                const float w1 = fw[oc * 27 + ich * 9 + dy * 3 + 1];
                const float w2 = fw[oc * 27 + ich * 9 + dy * 3 + 2];
                v2f W0 = {w0, w0}; v2f W1 = {w1, w1}; v2f W2 = {w2, w2};
#pragma unroll
                for (int c = 0; c < 4; ++c) {
                    acc[oc][c] = FMA2(win[c], W0,
                                 FMA2(win[c + 1], W1,
                                 FMA2(win[c + 2], W2, acc[oc][c])));
                }
            }
        }
    }
}

__global__ __launch_bounds__(256, 4) void conv_att_kernel(
    const float* __restrict__ x, const float* __restrict__ thumb,
    const float* __restrict__ feat, float* __restrict__ out)
{
    __shared__ float bufA[ASZ];
    __shared__ float bufB[BSZ];

    int id = blockIdx.x;
    const float* src; float* dst; int H, W, b, trow, tcol;
    if (id < 2048) {                 // big: 8 batches x (32 row x 8 col) tiles
        b = id >> 8; const int t = id & 255;
        H = 512; W = 512; trow = (t >> 3) * 16; tcol = (t & 7) * 64;
        src = x; dst = out;
    } else {                         // thumb: 8 batches x 4 row tiles
        const int i2 = id - 2048;
        b = i2 >> 2; trow = (i2 & 3) * 16; tcol = 0;
        H = 64; W = 64; src = thumb;
        dst = out + (size_t)8 * 3 * 512 * 512;
    }
    const float* fb = feat + b * 360;    // uniform -> scalar loads
    const int tid = threadIdx.x;

    // ---- stage0: issue ALL global loads first (regs), then write LDS ----
    // main: 3ch x 22 rows x 16 interior quads = 1056 units; 4 full rounds
    // + round 5 for tid<32. Loads issue back-to-back -> one HBM latency.
    const float* sbg = src + (size_t)b * 3 * H * W;
    float4 stv[4];
#pragma unroll
    for (int i = 0; i < 4; ++i) {
        const int q = tid + 256 * i;           // < 1024
        const int c = q / 352;                 // 352 = 22*16
        const int rem = q - c * 352;
        const int mr = rem >> 4;
        const int k  = rem & 15;
        const int gr = trow + mr - 3;
        const int gc0 = tcol + 4 * k;          // always in [0, W-4]
        float4 v = make_float4(0.f, 0.f, 0.f, 0.f);
        if ((unsigned)gr < (unsigned)H)
            v = *(const float4*)&sbg[(size_t)c * H * W + (size_t)gr * W + gc0];
        stv[i] = v;
    }
    const bool has5 = tid < 32;                // q = 1024..1055 (c=2)
    float4 st5 = make_float4(0.f, 0.f, 0.f, 0.f);
    if (has5) {
        const int q = tid + 1024;
        const int rem = q - 704;               // c = 2
        const int mr = rem >> 4;
        const int k  = rem & 15;
        const int gr = trow + mr - 3;
        const int gc0 = tcol + 4 * k;
        if ((unsigned)gr < (unsigned)H)
            st5 = *(const float4*)&sbg[(size_t)2 * H * W + (size_t)gr * W + gc0];
    }
    // halo: cols 0..3 (img tcol-4) and 68..71 (img tcol+64), 132 units
    const bool hasH = tid < 132;
    float4 hv = make_float4(0.f, 0.f, 0.f, 0.f);
    int hc = 0, hmr = 0, hside = 0;
    if (hasH) {
        hc = tid / 44;                         // 44 = 22*2
        const int rem = tid - hc * 44;
        hmr = rem >> 1;
        hside = rem & 1;
        const int gr = trow + hmr - 3;
        const int gc0 = tcol + (hside ? 64 : -4);
        const bool rok = (unsigned)gr < (unsigned)H;
        const float* gp = sbg + (size_t)hc * H * W + (size_t)(rok ? gr : 0) * W;
        if (rok && (unsigned)gc0 <= (unsigned)(W - 4)) {
            hv = *(const float4*)&gp[gc0];
        } else {
            hv.x = (rok && (unsigned)(gc0 + 0) < (unsigned)W) ? gp[gc0 + 0] : 0.f;
            hv.y = (rok && (unsigned)(gc0 + 1) < (unsigned)W) ? gp[gc0 + 1] : 0.f;
            hv.z = (rok && (unsigned)(gc0 + 2) < (unsigned)W) ? gp[gc0 + 2] : 0.f;
            hv.w = (rok && (unsigned)(gc0 + 3) < (unsigned)W) ? gp[gc0 + 3] : 0.f;
        }
    }
    // writes (transpose into col-major A)
#pragma unroll
    for (int i = 0; i < 4; ++i) {
        const int q = tid + 256 * i;
        const int c = q / 352;
        const int rem = q - c * 352;
        const int mr = rem >> 4;
        const int k  = rem & 15;
        float* bp = &bufA[c * CHSA + (4 * k + 4) * CSTRA + mr];
        bp[0] = stv[i].x; bp[CSTRA] = stv[i].y;
        bp[2 * CSTRA] = stv[i].z; bp[3 * CSTRA] = stv[i].w;
    }
    if (has5) {
        const int rem = tid + 1024 - 704;
        const int mr = rem >> 4;
        const int k  = rem & 15;
        float* bp = &bufA[2 * CHSA + (4 * k + 4) * CSTRA + mr];
        bp[0] = st5.x; bp[CSTRA] = st5.y; bp[2 * CSTRA] = st5.z; bp[3 * CSTRA] = st5.w;
    }
    if (hasH) {
        float* bp = &bufA[hc * CHSA + (hside ? 68 : 0) * CSTRA + hmr];
        bp[0] = hv.x; bp[CSTRA] = hv.y; bp[2 * CSTRA] = hv.z; bp[3 * CSTRA] = hv.w;
    }
    // zero pads: A col 72 (rows 0..21, conv1 gx=64 C-reads), B col 72
    // (rows 0..19, conv2 gx=64 C-reads). Disjoint thread ranges.
    if (tid < 66) {
        const int c = tid / 22, mr = tid - c * 22;
        bufA[c * CHSA + 72 * CSTRA + mr] = 0.f;
    } else if (tid < 126) {
        const int t2 = tid - 66;
        const int c = t2 / 20, r = t2 - c * 20;
        bufB[c * CHSB + 72 * CSTRB + r] = 0.f;
    }
    __syncthreads();

    // ---- phase 2: residual stash (reads A) + conv1 (A -> B) ----
    const int s3 = tid >> 4;             // strip 0..7 (valid for tid<128)
    const int gx3 = 4 * (tid & 15);
    v2f res2[3][4];
    if (tid < 128) {
#pragma unroll
        for (int ch = 0; ch < 3; ++ch)
#pragma unroll
            for (int c = 0; c < 4; ++c)
                res2[ch][c] = ldpair(&bufA[ch * CHSA + (gx3 + 4 + c) * CSTRA + (2 * s3 + 3)]);
    }
    // conv1: 10 strips (r0 = 2s-2, rows -2..17) x 18 quads = 180 units
    // main 160 (s=tid>>4, gx=4*(tid&15)); halo 20 on lanes 160..179.
    {
        const bool act1 = tid < 180;
        int s1, gx1;
        if (tid < 160) { s1 = tid >> 4; gx1 = 4 * (tid & 15); }
        else { const int v = tid - 160; s1 = v >> 1; gx1 = (v & 1) ? 64 : -4; }
        if (act1) {
            v2f acc[3][4];
            // rb = r0+2 = 2*s1 (A rows = img+3); B write row = r0+2 = 2*s1
            conv_rows_pk<CHSA, CSTRA>(bufA, fb, 2 * s1, gx1, acc);
#pragma unroll
            for (int oc = 0; oc < 3; ++oc)
#pragma unroll
                for (int c = 0; c < 4; ++c)
                    stpair(&bufB[oc * CHSB + (gx1 + 4 + c) * CSTRB + 2 * s1],
                           leaky2(acc[oc][c]));
        }
    }
    __syncthreads();

    // ---- phase 3: conv2 (B -> A; input rows dead, residual in regs) ----
    {
        const bool act2 = tid < 162;
        int s2, gx2;
        if (tid < 144) { s2 = tid >> 4; gx2 = 4 * (tid & 15); }
        else { const int v = tid - 144; s2 = v >> 1; gx2 = (v & 1) ? 64 : -4; }
        if (act2) {
            v2f acc[3][4];
            // r0 = 2s-1; rb = r0+1 = 2*s2 (B rows = img+2);
            // A write row = r0+3 = 2*s2+2 (A rows = img+3)
            conv_rows_pk<CHSB, CSTRB>(bufB, fb + 84, 2 * s2, gx2, acc);
#pragma unroll
            for (int oc = 0; oc < 3; ++oc)
#pragma unroll
                for (int c = 0; c < 4; ++c)
                    stpair(&bufA[oc * CHSA + (gx2 + 4 + c) * CSTRA + 2 * s2 + 2],
                           leaky2(acc[oc][c]));
        }
    }
    __syncthreads();

    // ---- phase 4: conv3 (reads A) + 1x1 chain + attention + store ----
    if (tid < 128) {
        v2f y[3][4];
        {
            v2f acc3[3][4];
            // r0 = 2*s3; rb = r0+2 = 2*s3+2
            conv_rows_pk<CHSA, CSTRA>(bufA, fb + 168, 2 * s3 + 2, gx3, acc3);
#pragma unroll
            for (int oc = 0; oc < 3; ++oc)
#pragma unroll
                for (int c = 0; c < 4; ++c) y[oc][c] = leaky2(acc3[oc][c]);
        }

        // 5x conv1x1 chain, packed over the row pair
#pragma unroll
        for (int lay = 0; lay < 5; ++lay) {
            const float* fw = fb + 252 + lay * 12;
            v2f W0 = {fw[0], fw[0]}; v2f W1 = {fw[1], fw[1]}; v2f W2 = {fw[2], fw[2]};
            v2f W3 = {fw[3], fw[3]}; v2f W4 = {fw[4], fw[4]}; v2f W5 = {fw[5], fw[5]};
            v2f W6 = {fw[6], fw[6]}; v2f W7 = {fw[7], fw[7]}; v2f W8 = {fw[8], fw[8]};
            v2f C0 = {fw[9], fw[9]}; v2f C1 = {fw[10], fw[10]}; v2f C2 = {fw[11], fw[11]};
            v2f z0[4], z1[4], z2[4];
#pragma unroll
            for (int c = 0; c < 4; ++c) {
                z0[c] = FMA2(y[0][c], W0, FMA2(y[1][c], W1, FMA2(y[2][c], W2, C0)));
                z1[c] = FMA2(y[0][c], W3, FMA2(y[1][c], W4, FMA2(y[2][c], W5, C1)));
                z2[c] = FMA2(y[0][c], W6, FMA2(y[1][c], W7, FMA2(y[2][c], W8, C2)));
            }
#pragma unroll
            for (int c = 0; c < 4; ++c) {
                y[0][c] = leaky2(z0[c]);
                y[1][c] = leaky2(z1[c]);
                y[2][c] = leaky2(z2[c]);
            }
        }

        // residual + attention + store (2 rows x 4 cols x 3 ch)
        const float invH = 1.f / (float)H;
        const float invW = 1.f / (float)W;
        const int gr0 = trow + 2 * s3;
        v2f h2 = {(float)gr0 * invH, (float)(gr0 + 1) * invH};
        const float wb = (float)(tcol + gx3) * invW;
        const v2f one = {1.f, 1.f};
#pragma unroll
        for (int ch = 0; ch < 3; ++ch) {
            const float* fp = fb + 312 + ch * 16;
            v2f PA0 = {fp[0], fp[0]},  PB0 = {fp[1], fp[1]},  PC0 = {fp[2], fp[2]},  PD0 = {fp[3], fp[3]};
            v2f PA1 = {fp[4], fp[4]},  PB1 = {fp[5], fp[5]},  PC1 = {fp[6], fp[6]},  PD1 = {fp[7], fp[7]};
            v2f PA2 = {fp[8], fp[8]},  PB2 = {fp[9], fp[9]},  PC2 = {fp[10], fp[10]}, PD2 = {fp[11], fp[11]};
            v2f PA3 = {fp[12], fp[12]}, PB3 = {fp[13], fp[13]}, PC3 = {fp[14], fp[14]}, PD3 = {fp[15], fp[15]};
            v2f t0 = FMA2(PA0, h2, PD0);
            v2f t1 = FMA2(PA1, h2, PD1);
            v2f t2 = FMA2(PA2, h2, PD2);
            v2f t3 = FMA2(PA3, h2, PD3);
            v2f o[4];
#pragma unroll
            for (int c = 0; c < 4; ++c) {
                const float wcs = wb + (float)c * invW;
                v2f Wc = {wcs, wcs};
                v2f v = y[ch][c] + res2[ch][c];
                v2f a = FMA2(PB0, Wc, FMA2(PC0, v, t0));
                a = a * FMA2(PB1, Wc, FMA2(PC1, v, t1));
                a = a * FMA2(PB2, Wc, FMA2(PC2, v, t2));
                a = a * FMA2(PB3, Wc, FMA2(PC3, v, t3));
                o[c] = v * (one + a);
            }
            float4 ra = make_float4(o[0].x, o[1].x, o[2].x, o[3].x);
            float4 rb = make_float4(o[0].y, o[1].y, o[2].y, o[3].y);
            float* dp = &dst[((size_t)(b * 3 + ch) * H + gr0) * W + tcol + gx3];
            *(float4*)dp = ra;
            *(float4*)(dp + W) = rb;
        }
    }
}

extern "C" void kernel_launch(void* const* d_in, const int* in_sizes, int n_in,
                              void* d_out, int out_size, void* d_ws, size_t ws_size,
                              hipStream_t stream) {
    const float* x = (const float*)d_in[0];       // (8,3,512,512)
    const float* thumb = (const float*)d_in[1];   // (8,3,64,64)
    const float* Wm = (const float*)d_in[2];      // (3,360)
    const float* bm = (const float*)d_in[3];      // (360,)
    float* out = (float*)d_out;
    float* feat = (float*)d_ws;                   // (8,360)

    prep_kernel<<<8, 384, 0, stream>>>(thumb, Wm, bm, feat);
    // 2048 big-image blocks + 32 thumb blocks
    conv_att_kernel<<<2080, 256, 0, stream>>>(x, thumb, feat, out);
}

// Round 9
// 106.473 us; speedup vs baseline: 1.4632x; 1.0361x over previous
//
#include <hip/hip_runtime.h>

// ---------------------------------------------------------------------------
// Per-batch dynamic conv stack + polynomial attention (f32).
//   feature (8,360) = mean(thumb,(2,3)) @ Wm + bm
//   conv_stack: residual + [3x conv3x3(SAME,leaky 0.2)] -> [5x conv1x1(leaky)]
//   attention:  out = y * (1 + prod_i(a*h + b*w + c*y + d)) per channel
// Outputs: x_out (8,3,512,512) then thumb_out (8,3,64,64), flat f32.
//
// R16 = R15 (pk-f32, col-major ping-pong LDS, 16x64 tiles, 256 thr) +
//   * dy-overlap load elimination: per (ich, window col) load the two
//     disjoint row pairs (rb,rb+1),(rb+2,rb+3); middle pair (rb+1,rb+2)
//     = {lo.y, hi.x} in regs. 54 -> 36 pair-loads/unit (-33% LDS issue,
//     the busiest pipe at ~44%), conflicts -1/3.
//   * conv3 + epilogue on ALL 4 waves via 2-col units (8 strips x 32 =
//     256 units): R15 ran the longest phase (conv3+chain+attention,
//     ~230 VALU instrs) on 2 of 4 waves. Per-wave phase cost halves.
//     Stores become 8B float2 (still 128B-contiguous per 16 lanes).
//   * Everything else identical to R15 (3 barriers, T14 stage0, ping-pong
//     A->B->A, residual in regs, aligned global writes).
// ---------------------------------------------------------------------------

typedef float v2f __attribute__((ext_vector_type(2)));
#define FMA2(a, b, c) __builtin_elementwise_fma((a), (b), (c))

__device__ __forceinline__ v2f leaky2(v2f v) {
    return __builtin_elementwise_max(v, v * 0.2f);
}

// align-4 LDS pair load/store: compiles to ds_read2_b32 / ds_write2_b32
__device__ __forceinline__ v2f ldpair(const float* p) {
    v2f r; __builtin_memcpy(&r, p, 8); return r;
}
__device__ __forceinline__ void stpair(float* p, v2f v) {
    __builtin_memcpy(p, &v, 8);
}

constexpr int NCOLS = 73;            // cols -4..67 + zero pad col 72
constexpr int CSTRA = 23;            // A: input/conv2-out, 22 rows + pad
constexpr int CHSA  = NCOLS * CSTRA; // 1679
constexpr int ASZ   = 3 * CHSA + 4;  // 20.2KB
constexpr int CSTRB = 21;            // B: conv1-out, 20 rows + pad
constexpr int CHSB  = NCOLS * CSTRB; // 1533
constexpr int BSZ   = 3 * CHSB + 4;  // 18.4KB

__global__ __launch_bounds__(384) void prep_kernel(
    const float* __restrict__ thumb, const float* __restrict__ Wm,
    const float* __restrict__ bm, float* __restrict__ feat)
{
    const int b = blockIdx.x;                // 8 blocks
    const int t = threadIdx.x;               // 384
    const int ch = t >> 7;                   // 0..2
    const int l  = t & 127;
    const float4* p = (const float4*)(thumb + (size_t)b * 3 * 4096);
    float s = 0.f;
#pragma unroll
    for (int k = 0; k < 8; ++k) {
        float4 v = p[ch * 1024 + l + k * 128];
        s += v.x + v.y + v.z + v.w;
    }
    __shared__ float red[384];
    red[t] = s;
    __syncthreads();
    for (int off = 64; off > 0; off >>= 1) {
        if (l < off) red[t] += red[t + off];
        __syncthreads();
    }
    if (t < 360) {
        const float sc = 1.f / 4096.f;
        const float m0 = red[0] * sc, m1 = red[128] * sc, m2 = red[256] * sc;
        feat[b * 360 + t] =
            fmaf(m0, Wm[t], fmaf(m1, Wm[360 + t], fmaf(m2, Wm[720 + t], bm[t])));
    }
}

// Packed 3x3 conv over a strip of 2 output rows x NC cols, all 3 och.
// acc[oc][c] = (row r0, row r0+1) packed. rb = buffer row of the first tap
// pair (taps cover buffer rows rb..rb+3). Per (ich, window col) load the
// two disjoint pairs p0=(rb,rb+1), p1=(rb+2,rb+3); middle pm={p0.y,p1.x}.
// gx may be -4 (halo): window col 0 clamps to col 3, feeding only
// discarded outputs.
template<int CHS_, int CSTR_, int NC>
__device__ __forceinline__ void conv_rows_pk(
    const float* __restrict__ buf, const float* __restrict__ fw,
    int rb, int gx, v2f acc[3][NC])
{
    const float b0 = fw[81], b1 = fw[82], b2 = fw[83];
#pragma unroll
    for (int c = 0; c < NC; ++c) {
        v2f i0 = {b0, b0}; v2f i1 = {b1, b1}; v2f i2 = {b2, b2};
        acc[0][c] = i0; acc[1][c] = i1; acc[2][c] = i2;
    }
    const int c0 = (gx < 0) ? 3 : gx + 3;
#pragma unroll
    for (int ich = 0; ich < 3; ++ich) {
        const int base = ich * CHS_ + rb;
        v2f p0[NC + 2], p1[NC + 2], pm[NC + 2];
#pragma unroll
        for (int k = 0; k < NC + 2; ++k) {
            const int cc = (k == 0) ? c0 : (gx + 3 + k);
            p0[k] = ldpair(&buf[base + cc * CSTR_]);
            p1[k] = ldpair(&buf[base + cc * CSTR_ + 2]);
            v2f m = {p0[k].y, p1[k].x};
            pm[k] = m;
        }
#pragma unroll
        for (int dy = 0; dy < 3; ++dy) {
#pragma unroll
            for (int oc = 0; oc < 3; ++oc) {
                const float w0 = fw[oc * 27 + ich * 9 + dy * 3 + 0];
                const float w1 = fw[oc * 27 + ich * 9 + dy * 3 + 1];
                const float w2 = fw[oc * 27 + ich * 9 + dy * 3 + 2];
                v2f W0 = {w0, w0}; v2f W1 = {w1, w1}; v2f W2 = {w2, w2};
#pragma unroll
                for (int c = 0; c < NC; ++c) {
                    const v2f wa = (dy == 0) ? p0[c]     : (dy == 1) ? pm[c]     : p1[c];
                    const v2f wb = (dy == 0) ? p0[c + 1] : (dy == 1) ? pm[c + 1] : p1[c + 1];
                    const v2f wc = (dy == 0) ? p0[c + 2] : (dy == 1) ? pm[c + 2] : p1[c + 2];
                    acc[oc][c] = FMA2(wa, W0, FMA2(wb, W1, FMA2(wc, W2, acc[oc][c])));
                }
            }
        }
    }
}

__global__ __launch_bounds__(256, 4) void conv_att_kernel(
    const float* __restrict__ x, const float* __restrict__ thumb,
    const float* __restrict__ feat, float* __restrict__ out)
{
    __shared__ float bufA[ASZ];
    __shared__ float bufB[BSZ];

    int id = blockIdx.x;
    const float* src; float* dst; int H, W, b, trow, tcol;
    if (id < 2048) {                 // big: 8 batches x (32 row x 8 col) tiles
        b = id >> 8; const int t = id & 255;
        H = 512; W = 512; trow = (t >> 3) * 16; tcol = (t & 7) * 64;
        src = x; dst = out;
    } else {                         // thumb: 8 batches x 4 row tiles
        const int i2 = id - 2048;
        b = i2 >> 2; trow = (i2 & 3) * 16; tcol = 0;
        H = 64; W = 64; src = thumb;
        dst = out + (size_t)8 * 3 * 512 * 512;
    }
    const float* fb = feat + b * 360;    // uniform -> scalar loads
    const int tid = threadIdx.x;

    // ---- stage0: issue ALL global loads first (regs), then write LDS ----
    const float* sbg = src + (size_t)b * 3 * H * W;
    float4 stv[4];
#pragma unroll
    for (int i = 0; i < 4; ++i) {
        const int q = tid + 256 * i;           // < 1024
        const int c = q / 352;                 // 352 = 22*16
        const int rem = q - c * 352;
        const int mr = rem >> 4;
        const int k  = rem & 15;
        const int gr = trow + mr - 3;
        const int gc0 = tcol + 4 * k;          // always in [0, W-4]
        float4 v = make_float4(0.f, 0.f, 0.f, 0.f);
        if ((unsigned)gr < (unsigned)H)
            v = *(const float4*)&sbg[(size_t)c * H * W + (size_t)gr * W + gc0];
        stv[i] = v;
    }
    const bool has5 = tid < 32;                // q = 1024..1055 (c=2)
    float4 st5 = make_float4(0.f, 0.f, 0.f, 0.f);
    if (has5) {
        const int q = tid + 1024;
        const int rem = q - 704;               // c = 2
        const int mr = rem >> 4;
        const int k  = rem & 15;
        const int gr = trow + mr - 3;
        const int gc0 = tcol + 4 * k;
        if ((unsigned)gr < (unsigned)H)
            st5 = *(const float4*)&sbg[(size_t)2 * H * W + (size_t)gr * W + gc0];
    }
    // halo: cols 0..3 (img tcol-4) and 68..71 (img tcol+64), 132 units
    const bool hasH = tid < 132;
    float4 hv = make_float4(0.f, 0.f, 0.f, 0.f);
    int hc = 0, hmr = 0, hside = 0;
    if (hasH) {
        hc = tid / 44;                         // 44 = 22*2
        const int rem = tid - hc * 44;
        hmr = rem >> 1;
        hside = rem & 1;
        const int gr = trow + hmr - 3;
        const int gc0 = tcol + (hside ? 64 : -4);
        const bool rok = (unsigned)gr < (unsigned)H;
        const float* gp = sbg + (size_t)hc * H * W + (size_t)(rok ? gr : 0) * W;
        if (rok && (unsigned)gc0 <= (unsigned)(W - 4)) {
            hv = *(const float4*)&gp[gc0];
        } else {
            hv.x = (rok && (unsigned)(gc0 + 0) < (unsigned)W) ? gp[gc0 + 0] : 0.f;
            hv.y = (rok && (unsigned)(gc0 + 1) < (unsigned)W) ? gp[gc0 + 1] : 0.f;
            hv.z = (rok && (unsigned)(gc0 + 2) < (unsigned)W) ? gp[gc0 + 2] : 0.f;
            hv.w = (rok && (unsigned)(gc0 + 3) < (unsigned)W) ? gp[gc0 + 3] : 0.f;
        }
    }
    // writes (transpose into col-major A)
#pragma unroll
    for (int i = 0; i < 4; ++i) {
        const int q = tid + 256 * i;
        const int c = q / 352;
        const int rem = q - c * 352;
        const int mr = rem >> 4;
        const int k  = rem & 15;
        float* bp = &bufA[c * CHSA + (4 * k + 4) * CSTRA + mr];
        bp[0] = stv[i].x; bp[CSTRA] = stv[i].y;
        bp[2 * CSTRA] = stv[i].z; bp[3 * CSTRA] = stv[i].w;
    }
    if (has5) {
        const int rem = tid + 1024 - 704;
        const int mr = rem >> 4;
        const int k  = rem & 15;
        float* bp = &bufA[2 * CHSA + (4 * k + 4) * CSTRA + mr];
        bp[0] = st5.x; bp[CSTRA] = st5.y; bp[2 * CSTRA] = st5.z; bp[3 * CSTRA] = st5.w;
    }
    if (hasH) {
        float* bp = &bufA[hc * CHSA + (hside ? 68 : 0) * CSTRA + hmr];
        bp[0] = hv.x; bp[CSTRA] = hv.y; bp[2 * CSTRA] = hv.z; bp[3 * CSTRA] = hv.w;
    }
    // zero pads: A col 72 (rows 0..21), B col 72 (rows 0..19)
    if (tid < 66) {
        const int c = tid / 22, mr = tid - c * 22;
        bufA[c * CHSA + 72 * CSTRA + mr] = 0.f;
    } else if (tid < 126) {
        const int t2 = tid - 66;
        const int c = t2 / 20, r = t2 - c * 20;
        bufB[c * CHSB + 72 * CSTRB + r] = 0.f;
    }
    __syncthreads();

    // ---- phase 2: residual stash (reads A) + conv1 (A -> B) ----
    // epilogue mapping (all 256 threads): strip s3e rows (2s3e, 2s3e+1),
    // cols gx3e, gx3e+1
    const int s3e = tid >> 5;            // 0..7
    const int gx3e = 2 * (tid & 31);     // 0..62
    v2f res2[3][2];
#pragma unroll
    for (int ch = 0; ch < 3; ++ch)
#pragma unroll
        for (int c = 0; c < 2; ++c)
            res2[ch][c] = ldpair(&bufA[ch * CHSA + (gx3e + 4 + c) * CSTRA + (2 * s3e + 3)]);
    // conv1: 10 strips (r0 = 2s-2) x 18 quads = 180 units
    {
        const bool act1 = tid < 180;
        int s1, gx1;
        if (tid < 160) { s1 = tid >> 4; gx1 = 4 * (tid & 15); }
        else { const int v = tid - 160; s1 = v >> 1; gx1 = (v & 1) ? 64 : -4; }
        if (act1) {
            v2f acc[3][4];
            // rb = 2*s1 (A rows = img+3); B write row = 2*s1 (B rows = img+2)
            conv_rows_pk<CHSA, CSTRA, 4>(bufA, fb, 2 * s1, gx1, acc);
#pragma unroll
            for (int oc = 0; oc < 3; ++oc)
#pragma unroll
                for (int c = 0; c < 4; ++c)
                    stpair(&bufB[oc * CHSB + (gx1 + 4 + c) * CSTRB + 2 * s1],
                           leaky2(acc[oc][c]));
        }
    }
    __syncthreads();

    // ---- phase 3: conv2 (B -> A; input rows dead, residual in regs) ----
    {
        const bool act2 = tid < 162;
        int s2, gx2;
        if (tid < 144) { s2 = tid >> 4; gx2 = 4 * (tid & 15); }
        else { const int v = tid - 144; s2 = v >> 1; gx2 = (v & 1) ? 64 : -4; }
        if (act2) {
            v2f acc[3][4];
            // rb = 2*s2 (B rows = img+2); A write row = 2*s2+2 (A rows = img+3)
            conv_rows_pk<CHSB, CSTRB, 4>(bufB, fb + 84, 2 * s2, gx2, acc);
#pragma unroll
            for (int oc = 0; oc < 3; ++oc)
#pragma unroll
                for (int c = 0; c < 4; ++c)
                    stpair(&bufA[oc * CHSA + (gx2 + 4 + c) * CSTRA + 2 * s2 + 2],
                           leaky2(acc[oc][c]));
        }
    }
    __syncthreads();

    // ---- phase 4: conv3 (2-col units, ALL 256 threads) + 1x1 chain
    //      + residual + attention + 8B stores ----
    {
        v2f y[3][2];
        {
            v2f acc3[3][2];
            // rb = 2*s3e+2 (A rows = img+3, first tap img row 2s3e-1)
            conv_rows_pk<CHSA, CSTRA, 2>(bufA, fb + 168, 2 * s3e + 2, gx3e, acc3);
#pragma unroll
            for (int oc = 0; oc < 3; ++oc)
#pragma unroll
                for (int c = 0; c < 2; ++c) y[oc][c] = leaky2(acc3[oc][c]);
        }

        // 5x conv1x1 chain, packed over the row pair
#pragma unroll
        for (int lay = 0; lay < 5; ++lay) {
            const float* fw = fb + 252 + lay * 12;
            v2f W0 = {fw[0], fw[0]}; v2f W1 = {fw[1], fw[1]}; v2f W2 = {fw[2], fw[2]};
            v2f W3 = {fw[3], fw[3]}; v2f W4 = {fw[4], fw[4]}; v2f W5 = {fw[5], fw[5]};
            v2f W6 = {fw[6], fw[6]}; v2f W7 = {fw[7], fw[7]}; v2f W8 = {fw[8], fw[8]};
            v2f C0 = {fw[9], fw[9]}; v2f C1 = {fw[10], fw[10]}; v2f C2 = {fw[11], fw[11]};
            v2f z0[2], z1[2], z2[2];
#pragma unroll
            for (int c = 0; c < 2; ++c) {
                z0[c] = FMA2(y[0][c], W0, FMA2(y[1][c], W1, FMA2(y[2][c], W2, C0)));
                z1[c] = FMA2(y[0][c], W3, FMA2(y[1][c], W4, FMA2(y[2][c], W5, C1)));
                z2[c] = FMA2(y[0][c], W6, FMA2(y[1][c], W7, FMA2(y[2][c], W8, C2)));
            }
#pragma unroll
            for (int c = 0; c < 2; ++c) {
                y[0][c] = leaky2(z0[c]);
                y[1][c] = leaky2(z1[c]);
                y[2][c] = leaky2(z2[c]);
            }
        }

        // residual + attention + store (2 rows x 2 cols x 3 ch)
        const float invH = 1.f / (float)H;
        const float invW = 1.f / (float)W;
        const int gr0 = trow + 2 * s3e;
        v2f h2 = {(float)gr0 * invH, (float)(gr0 + 1) * invH};
        const float wb = (float)(tcol + gx3e) * invW;
        const v2f one = {1.f, 1.f};
#pragma unroll
        for (int ch = 0; ch < 3; ++ch) {
            const float* fp = fb + 312 + ch * 16;
            v2f PA0 = {fp[0], fp[0]},  PB0 = {fp[1], fp[1]},  PC0 = {fp[2], fp[2]},  PD0 = {fp[3], fp[3]};
            v2f PA1 = {fp[4], fp[4]},  PB1 = {fp[5], fp[5]},  PC1 = {fp[6], fp[6]},  PD1 = {fp[7], fp[7]};
            v2f PA2 = {fp[8], fp[8]},  PB2 = {fp[9], fp[9]},  PC2 = {fp[10], fp[10]}, PD2 = {fp[11], fp[11]};
            v2f PA3 = {fp[12], fp[12]}, PB3 = {fp[13], fp[13]}, PC3 = {fp[14], fp[14]}, PD3 = {fp[15], fp[15]};
            v2f t0 = FMA2(PA0, h2, PD0);
            v2f t1 = FMA2(PA1, h2, PD1);
            v2f t2 = FMA2(PA2, h2, PD2);
            v2f t3 = FMA2(PA3, h2, PD3);
            v2f o[2];
#pragma unroll
            for (int c = 0; c < 2; ++c) {
                const float wcs = wb + (float)c * invW;
                v2f Wc = {wcs, wcs};
                v2f v = y[ch][c] + res2[ch][c];
                v2f a = FMA2(PB0, Wc, FMA2(PC0, v, t0));
                a = a * FMA2(PB1, Wc, FMA2(PC1, v, t1));
                a = a * FMA2(PB2, Wc, FMA2(PC2, v, t2));
                a = a * FMA2(PB3, Wc, FMA2(PC3, v, t3));
                o[c] = v * (one + a);
            }
            v2f ra = {o[0].x, o[1].x};
            v2f rb2 = {o[0].y, o[1].y};
            float* dp = &dst[((size_t)(b * 3 + ch) * H + gr0) * W + tcol + gx3e];
            __builtin_memcpy(dp, &ra, 8);
            __builtin_memcpy(dp + W, &rb2, 8);
        }
    }
}

extern "C" void kernel_launch(void* const* d_in, const int* in_sizes, int n_in,
                              void* d_out, int out_size, void* d_ws, size_t ws_size,
                              hipStream_t stream) {
    const float* x = (const float*)d_in[0];       // (8,3,512,512)
    const float* thumb = (const float*)d_in[1];   // (8,3,64,64)
    const float* Wm = (const float*)d_in[2];      // (3,360)
    const float* bm = (const float*)d_in[3];      // (360,)
    float* out = (float*)d_out;
    float* feat = (float*)d_ws;                   // (8,360)

    prep_kernel<<<8, 384, 0, stream>>>(thumb, Wm, bm, feat);
    // 2048 big-image blocks + 32 thumb blocks
    conv_att_kernel<<<2080, 256, 0, stream>>>(x, thumb, feat, out);
}